// Round 3
// baseline (2654.217 us; speedup 1.0000x reference)
//
#include <hip/hip_runtime.h>
#include <hip/hip_bf16.h>

// PoolingAttention: B=64 N=197 C=768 H=12 D=64.
// out = [B*N*C] attention output ++ [B*160] keep_index, both in the problem's
// output dtype (bf16 or fp32 — detected at runtime from the input encoding).
//
// Dtype-adaptive: detect_kernel reads x as u16; bf16-encoded N(0,1) data has
// exponent field <= ~130, while fp32 data misread as u16 pairs has ~45% wild
// exponents (>=140). Flag lives in ws[0..3]; every kernel branches on it
// (wave-uniform scalar branch, graph-safe since it's recomputed per call).

#define BB 64
#define NN 197
#define CC 768
#define HH 12
#define DD 64
#define KEEP 160
#define SCALE_F 0.125f   // 64^-0.5
#define OUT0_ELEMS ((size_t)BB * NN * CC)   // 9,682,944

typedef __attribute__((ext_vector_type(8))) short bf16x8_t;
typedef __attribute__((ext_vector_type(4))) float f32x4_t;

__device__ __forceinline__ float b2f(unsigned short u) {
  union { unsigned u; float f; } cv; cv.u = (unsigned)u << 16; return cv.f;
}
__device__ __forceinline__ unsigned short f2b(float f) {   // RNE, finite inputs
  union { float f; unsigned u; } cv; cv.f = f;
  return (unsigned short)((cv.u + 0x7FFFu + ((cv.u >> 16) & 1u)) >> 16);
}
// mixed-dtype scalar load: flag=1 -> fp32, flag=0 -> bf16
__device__ __forceinline__ float ldmix(const void* p, size_t i, int f32) {
  return f32 ? ((const float*)p)[i] : b2f(((const unsigned short*)p)[i]);
}

// ---------------------------------------------------------------------------
__global__ void detect_kernel(const void* x, int* flag) {
  __shared__ int cnt;
  if (threadIdx.x == 0) cnt = 0;
  __syncthreads();
  const unsigned short* u = (const unsigned short*)x;
  int wild = 0;
  for (int i = threadIdx.x; i < 4096; i += 256) {
    int e = (u[i] >> 7) & 0xFF;
    wild += (e >= 140);
  }
  atomicAdd(&cnt, wild);
  __syncthreads();
  if (threadIdx.x == 0) *flag = (cnt > 100) ? 1 : 0;
}

// normalize any fp input segment to bf16 in ws
__global__ void cvt_bf16(const void* src, size_t elem_off,
                         unsigned short* dst, int n, const int* flag) {
  int i = blockIdx.x * 256 + threadIdx.x;
  if (i >= n) return;
  const int f32 = *flag;
  if (f32) dst[i] = f2b(((const float*)src)[elem_off + i]);
  else     dst[i] = ((const unsigned short*)src)[elem_off + i];
}
__global__ void cvt_f32(const void* src, float* dst, int n, const int* flag) {
  int i = blockIdx.x * 256 + threadIdx.x;
  if (i >= n) return;
  dst[i] = ldmix(src, i, *flag);
}

// ---------------------------------------------------------------------------
// qkvc = xb_c @ wb.T ; bf16 operands from ws; 16x16x32 MFMA (m97 layout).
// ---------------------------------------------------------------------------
__global__ __launch_bounds__(256, 4) void qkv_gemm(
    const unsigned short* __restrict__ xb,
    const unsigned short* __restrict__ wb,
    unsigned short* __restrict__ qkvc, int Mc, int bc) {
  const int wave = threadIdx.x >> 6;
  const int lane = threadIdx.x & 63;
  const int l16  = lane & 15;
  const int quad = lane >> 4;
  const int m_base = blockIdx.x * 16;
  const int c_base = blockIdx.y * 64 + wave * 16;

  int row = m_base + l16; if (row >= Mc) row = Mc - 1;
  const short* xp = (const short*)xb + (size_t)row * CC + quad * 8;
  const short* wp = (const short*)wb + (size_t)(c_base + l16) * CC + quad * 8;

  f32x4_t acc = {0.f, 0.f, 0.f, 0.f};
  #pragma unroll 4
  for (int k = 0; k < CC; k += 32) {
    bf16x8_t a = *(const bf16x8_t*)(xp + k);
    bf16x8_t b = *(const bf16x8_t*)(wp + k);
    acc = __builtin_amdgcn_mfma_f32_16x16x32_bf16(a, b, acc, 0, 0, 0);
  }

  const int c = c_base + l16;
  const int s = c / CC;
  const int hc = (c - s * CC) >> 6;
  const int d = c & 63;
  #pragma unroll
  for (int i = 0; i < 4; i++) {
    int m = m_base + quad * 4 + i;
    if (m < Mc) {
      int bb = m / NN;
      int n  = m - bb * NN;
      qkvc[((((size_t)s * bc + bb) * HH + hc) * NN + n) * DD + d] = f2b(acc[i]);
    }
  }
}

// ---------------------------------------------------------------------------
// per (bb,h) attention; K fp32 in LDS; 1 thread/query; 2-pass softmax fp32.
// ---------------------------------------------------------------------------
__global__ __launch_bounds__(256, 1) void attn_kernel(
    const unsigned short* __restrict__ qkvc, int bc,
    unsigned short* __restrict__ Yc) {
  const int bh = blockIdx.x;
  const int bb = bh / HH;
  const int h  = bh % HH;
  const size_t mat = (size_t)bc * HH * NN * DD;
  const unsigned short* q = qkvc + ((size_t)bb * HH + h) * NN * DD;
  const unsigned short* k = q + mat;
  const unsigned short* v = q + 2 * mat;

  __shared__ float ks[NN * DD];  // 50,432 B
  {
    const ushort4* k4 = (const ushort4*)k;
    for (int i = threadIdx.x; i < NN * DD / 4; i += 256) {
      ushort4 t = k4[i];
      ks[i*4+0] = b2f(t.x); ks[i*4+1] = b2f(t.y);
      ks[i*4+2] = b2f(t.z); ks[i*4+3] = b2f(t.w);
    }
  }
  __syncthreads();

  const int r = threadIdx.x;
  if (r < NN) {
    float qr[DD];
    {
      const ushort4* q4 = (const ushort4*)(q + (size_t)r * DD);
      #pragma unroll
      for (int j = 0; j < 16; j++) {
        ushort4 t = q4[j];
        qr[j*4+0] = b2f(t.x); qr[j*4+1] = b2f(t.y);
        qr[j*4+2] = b2f(t.z); qr[j*4+3] = b2f(t.w);
      }
    }
    float mx = -1e30f;
    for (int m = 0; m < NN; m++) {
      const float4* kp = (const float4*)(ks + m * DD);
      float s = 0.f;
      #pragma unroll
      for (int j4 = 0; j4 < 16; j4++) {
        float4 kk = kp[j4];
        s += qr[j4*4+0]*kk.x + qr[j4*4+1]*kk.y + qr[j4*4+2]*kk.z + qr[j4*4+3]*kk.w;
      }
      mx = fmaxf(mx, s * SCALE_F);
    }
    float o[DD];
    #pragma unroll
    for (int j = 0; j < DD; j++) o[j] = 0.f;
    float sum = 0.f;
    for (int m = 0; m < NN; m++) {
      const float4* kp = (const float4*)(ks + m * DD);
      float s = 0.f;
      #pragma unroll
      for (int j4 = 0; j4 < 16; j4++) {
        float4 kk = kp[j4];
        s += qr[j4*4+0]*kk.x + qr[j4*4+1]*kk.y + qr[j4*4+2]*kk.z + qr[j4*4+3]*kk.w;
      }
      float p = __expf(s * SCALE_F - mx);
      sum += p;
      const ushort4* vp = (const ushort4*)(v + (size_t)m * DD);
      #pragma unroll
      for (int j4 = 0; j4 < 16; j4++) {
        ushort4 vv = vp[j4];
        o[j4*4+0] += p * b2f(vv.x); o[j4*4+1] += p * b2f(vv.y);
        o[j4*4+2] += p * b2f(vv.z); o[j4*4+3] += p * b2f(vv.w);
      }
    }
    const float inv = 1.0f / sum;
    unsigned short* yp = Yc + ((size_t)bb * NN + r) * CC + h * DD;
    #pragma unroll
    for (int j = 0; j < DD; j++) yp[j] = f2b(o[j] * inv);
  }
}

// ---------------------------------------------------------------------------
// top-k from RAW inputs (native dtype, fp32 math — matches np in both
// scenarios). w[n] = sum_h |x_n . g_h|, g_h = Wk_h^T q_cls_h.
// ---------------------------------------------------------------------------
__global__ __launch_bounds__(256, 1) void topk_kernel(
    const void* __restrict__ x, const void* __restrict__ qkv_w,
    void* __restrict__ out, const int* __restrict__ flag) {
  const int b = blockIdx.x;
  const int f32 = *flag;
  __shared__ float x0[CC];
  __shared__ float qc[CC];
  __shared__ float g[HH * CC];   // 36 KB
  __shared__ float wgt[NN];
  __shared__ int   rank[NN];

  const size_t xb0 = (size_t)b * NN * CC;

  for (int i = threadIdx.x; i < CC; i += 256) x0[i] = ldmix(x, xb0 + i, f32);
  __syncthreads();

  for (int i = threadIdx.x; i < CC; i += 256) {   // q_cls rows of Wq
    const size_t ro = (size_t)i * CC;
    float s = 0.f;
    for (int c = 0; c < CC; c++) s += x0[c] * ldmix(qkv_w, ro + c, f32);
    qc[i] = s;
  }
  __syncthreads();

  {  // g[h][c] = sum_d Wk[768+h*64+d][c] * qc[h*64+d], coalesced in c
    const int c0 = threadIdx.x, c1 = c0 + 256, c2 = c1 + 256;
    for (int h = 0; h < HH; h++) {
      float a0 = 0.f, a1 = 0.f, a2 = 0.f;
      for (int d = 0; d < DD; d++) {
        const size_t ro = (size_t)(CC + h * DD + d) * CC;
        float qv = qc[h * DD + d];
        a0 += ldmix(qkv_w, ro + c0, f32) * qv;
        a1 += ldmix(qkv_w, ro + c1, f32) * qv;
        a2 += ldmix(qkv_w, ro + c2, f32) * qv;
      }
      g[h * CC + c0] = a0; g[h * CC + c1] = a1; g[h * CC + c2] = a2;
    }
  }
  __syncthreads();

  const int n = threadIdx.x;
  if (n < NN) {
    const size_t xr = xb0 + (size_t)n * CC;
    float acc = 0.f;
    for (int h = 0; h < HH; h++) {
      const float* gh = &g[h * CC];
      float s = 0.f;
      for (int c = 0; c < CC; c++) s += ldmix(x, xr + c, f32) * gh[c];
      acc += fabsf(s);
    }
    wgt[n] = acc;
  }
  __syncthreads();
  if (n < NN) {
    float wi = wgt[n];
    int rk = 0;
    for (int j = 0; j < NN; j++) {
      float wj = wgt[j];
      rk += (wj > wi) || (wj == wi && j < n);   // stable top_k tie-break
    }
    rank[n] = rk;
  }
  __syncthreads();
  if (n < NN && rank[n] < KEEP) {
    int pos = 0;
    for (int j = 0; j < n; j++) pos += (rank[j] < KEEP);
    const size_t oi = OUT0_ELEMS + (size_t)b * KEEP + pos;
    if (f32) ((float*)out)[oi] = (float)n;
    else ((unsigned short*)out)[oi] = f2b((float)n);
  }
}

// ---------------------------------------------------------------------------
// out_chunk = Yc @ pw.T + pbf ; dual-dtype store.
// ---------------------------------------------------------------------------
__global__ __launch_bounds__(256, 4) void proj_gemm(
    const unsigned short* __restrict__ Yc,
    const unsigned short* __restrict__ pw,
    const float* __restrict__ pbf,
    void* __restrict__ out, size_t out_elem_off, int Mc,
    const int* __restrict__ flag) {
  const int wave = threadIdx.x >> 6;
  const int lane = threadIdx.x & 63;
  const int l16  = lane & 15;
  const int quad = lane >> 4;
  const int m_base = blockIdx.x * 16;
  const int c_base = blockIdx.y * 64 + wave * 16;

  int row = m_base + l16; if (row >= Mc) row = Mc - 1;
  const short* yp = (const short*)Yc + (size_t)row * CC + quad * 8;
  const short* wp = (const short*)pw + (size_t)(c_base + l16) * CC + quad * 8;

  f32x4_t acc = {0.f, 0.f, 0.f, 0.f};
  #pragma unroll 4
  for (int k = 0; k < CC; k += 32) {
    bf16x8_t a  = *(const bf16x8_t*)(yp + k);
    bf16x8_t bf = *(const bf16x8_t*)(wp + k);
    acc = __builtin_amdgcn_mfma_f32_16x16x32_bf16(a, bf, acc, 0, 0, 0);
  }

  const int c = c_base + l16;
  const float bv = pbf[c];
  const int f32 = *flag;
  #pragma unroll
  for (int i = 0; i < 4; i++) {
    int m = m_base + quad * 4 + i;
    if (m < Mc) {
      float val = acc[i] + bv;
      size_t oi = out_elem_off + (size_t)m * CC + c;
      if (f32) ((float*)out)[oi] = val;
      else ((unsigned short*)out)[oi] = f2b(val);
    }
  }
}

// ---------------------------------------------------------------------------
extern "C" void kernel_launch(void* const* d_in, const int* in_sizes, int n_in,
                              void* d_out, int out_size, void* d_ws, size_t ws_size,
                              hipStream_t stream) {
  const void* x      = d_in[0];
  const void* qkv_w  = d_in[1];
  const void* proj_w = d_in[2];
  const void* proj_b = d_in[3];

  // ws layout (bytes):
  //   [0,256)                       flag
  //   wb  bf16 [2304*768]           3,538,944
  //   pw  bf16 [768*768]            1,179,648
  //   pbf f32  [768]                3,072
  //   chunk region: xb_c bf16 [Mc*CC] ++ qkvc bf16 [3*bc*H*N*D] ++ Yc bf16 [Mc*CC]
  char* wsb = (char*)d_ws;
  int* flag = (int*)wsb;
  unsigned short* wb  = (unsigned short*)(wsb + 256);
  unsigned short* pw  = (unsigned short*)(wsb + 256 + 3538944);
  float*          pbf = (float*)(wsb + 256 + 3538944 + 1179648);
  char* chunk = wsb + 4721920;

  const size_t per_batch = (size_t)NN * CC * 2   // xb_c
                         + 3ull * HH * NN * DD * 2  // qkvc
                         + (size_t)NN * CC * 2;  // Yc   = 1,512,960
  int Bc = BB;
  while (Bc > 1 && 4721920ull + (size_t)Bc * per_batch > ws_size) Bc >>= 1;

  unsigned short* xb   = (unsigned short*)chunk;
  unsigned short* qkvc = xb + (size_t)Bc * NN * CC;
  unsigned short* Yc   = qkvc + 3ull * Bc * HH * NN * DD;

  detect_kernel<<<1, 256, 0, stream>>>(x, flag);
  cvt_bf16<<<(3 * CC * CC + 255) / 256, 256, 0, stream>>>(qkv_w, 0, wb, 3 * CC * CC, flag);
  cvt_bf16<<<(CC * CC + 255) / 256, 256, 0, stream>>>(proj_w, 0, pw, CC * CC, flag);
  cvt_f32<<<(CC + 255) / 256, 256, 0, stream>>>(proj_b, pbf, CC, flag);
  topk_kernel<<<dim3(BB), 256, 0, stream>>>(x, qkv_w, d_out, flag);

  const int nChunks = (BB + Bc - 1) / Bc;
  for (int cb = 0; cb < nChunks; cb++) {
    const int b0 = cb * Bc;
    const int bc = (BB - b0 < Bc) ? (BB - b0) : Bc;
    const int Mc = bc * NN;
    cvt_bf16<<<(Mc * CC + 255) / 256, 256, 0, stream>>>(
        x, (size_t)b0 * NN * CC, xb, Mc * CC, flag);
    qkv_gemm<<<dim3((Mc + 15) / 16, 36), 256, 0, stream>>>(xb, wb, qkvc, Mc, bc);
    attn_kernel<<<dim3(bc * HH), 256, 0, stream>>>(qkvc, bc, Yc);
    proj_gemm<<<dim3((Mc + 15) / 16, 12), 256, 0, stream>>>(
        Yc, pw, pbf, d_out, (size_t)b0 * NN * CC, Mc, flag);
  }
}

// Round 4
// 1531.289 us; speedup vs baseline: 1.7333x; 1.7333x over previous
//
#include <hip/hip_runtime.h>
#include <hip/hip_bf16.h>

// PoolingAttention: B=64 N=197 C=768 H=12 D=64.
// out = [B*N*C] attention output ++ [B*160] keep_index (dtype detected: bf16
// or fp32 — confirmed fp32 on this harness, detector kept for robustness).
//
// Pipeline: detect -> cvt weights/x to bf16 -> MFMA qkv GEMM -> per-head
// attention -> MFMA proj GEMM. Top-k path: 4 small fp32-exact kernels
// (qcls/gmat/score/rank) — replaces the old 1-block-per-batch kernel that ran
// at 3% occupancy and re-fetched Wq per batch (1270 us -> target ~30 us).

#define BB 64
#define NN 197
#define CC 768
#define HH 12
#define DD 64
#define KEEP 160
#define SCALE_F 0.125f   // 64^-0.5
#define OUT0_ELEMS ((size_t)BB * NN * CC)   // 9,682,944

typedef __attribute__((ext_vector_type(8))) short bf16x8_t;
typedef __attribute__((ext_vector_type(4))) float f32x4_t;

__device__ __forceinline__ float b2f(unsigned short u) {
  union { unsigned u; float f; } cv; cv.u = (unsigned)u << 16; return cv.f;
}
__device__ __forceinline__ unsigned short f2b(float f) {   // RNE, finite
  union { float f; unsigned u; } cv; cv.f = f;
  return (unsigned short)((cv.u + 0x7FFFu + ((cv.u >> 16) & 1u)) >> 16);
}
__device__ __forceinline__ float ldmix(const void* p, size_t i, int f32) {
  return f32 ? ((const float*)p)[i] : b2f(((const unsigned short*)p)[i]);
}

// ---------------------------------------------------------------------------
__global__ void detect_kernel(const void* x, int* flag) {
  __shared__ int cnt;
  if (threadIdx.x == 0) cnt = 0;
  __syncthreads();
  const unsigned short* u = (const unsigned short*)x;
  int wild = 0;
  for (int i = threadIdx.x; i < 4096; i += 256) {
    int e = (u[i] >> 7) & 0xFF;
    wild += (e >= 140);
  }
  atomicAdd(&cnt, wild);
  __syncthreads();
  if (threadIdx.x == 0) *flag = (cnt > 100) ? 1 : 0;
}

__global__ void cvt_bf16(const void* src, size_t elem_off,
                         unsigned short* dst, int n, const int* flag) {
  int i = blockIdx.x * 256 + threadIdx.x;
  if (i >= n) return;
  const int f32 = *flag;
  if (f32) dst[i] = f2b(((const float*)src)[elem_off + i]);
  else     dst[i] = ((const unsigned short*)src)[elem_off + i];
}
__global__ void cvt_f32(const void* src, float* dst, int n, const int* flag) {
  int i = blockIdx.x * 256 + threadIdx.x;
  if (i >= n) return;
  dst[i] = ldmix(src, i, *flag);
}

// ---------------------------------------------------------------------------
// qkvc = xb_c @ wb.T ; bf16 operands from ws; 16x16x32 MFMA (m97 layout).
// ---------------------------------------------------------------------------
__global__ __launch_bounds__(256, 4) void qkv_gemm(
    const unsigned short* __restrict__ xb,
    const unsigned short* __restrict__ wb,
    unsigned short* __restrict__ qkvc, int Mc, int bc) {
  const int wave = threadIdx.x >> 6;
  const int lane = threadIdx.x & 63;
  const int l16  = lane & 15;
  const int quad = lane >> 4;
  const int m_base = blockIdx.x * 16;
  const int c_base = blockIdx.y * 64 + wave * 16;

  int row = m_base + l16; if (row >= Mc) row = Mc - 1;
  const short* xp = (const short*)xb + (size_t)row * CC + quad * 8;
  const short* wp = (const short*)wb + (size_t)(c_base + l16) * CC + quad * 8;

  f32x4_t acc = {0.f, 0.f, 0.f, 0.f};
  #pragma unroll 4
  for (int k = 0; k < CC; k += 32) {
    bf16x8_t a = *(const bf16x8_t*)(xp + k);
    bf16x8_t b = *(const bf16x8_t*)(wp + k);
    acc = __builtin_amdgcn_mfma_f32_16x16x32_bf16(a, b, acc, 0, 0, 0);
  }

  const int c = c_base + l16;
  const int s = c / CC;
  const int hc = (c - s * CC) >> 6;
  const int d = c & 63;
  #pragma unroll
  for (int i = 0; i < 4; i++) {
    int m = m_base + quad * 4 + i;
    if (m < Mc) {
      int bb = m / NN;
      int n  = m - bb * NN;
      qkvc[((((size_t)s * bc + bb) * HH + hc) * NN + n) * DD + d] = f2b(acc[i]);
    }
  }
}

// ---------------------------------------------------------------------------
// per (bb,h) attention; K fp32 in LDS; 1 thread/query; 2-pass softmax fp32.
// ---------------------------------------------------------------------------
__global__ __launch_bounds__(256, 1) void attn_kernel(
    const unsigned short* __restrict__ qkvc, int bc,
    unsigned short* __restrict__ Yc) {
  const int bh = blockIdx.x;
  const int bb = bh / HH;
  const int h  = bh % HH;
  const size_t mat = (size_t)bc * HH * NN * DD;
  const unsigned short* q = qkvc + ((size_t)bb * HH + h) * NN * DD;
  const unsigned short* k = q + mat;
  const unsigned short* v = q + 2 * mat;

  __shared__ float ks[NN * DD];  // 50,432 B
  {
    const ushort4* k4 = (const ushort4*)k;
    for (int i = threadIdx.x; i < NN * DD / 4; i += 256) {
      ushort4 t = k4[i];
      ks[i*4+0] = b2f(t.x); ks[i*4+1] = b2f(t.y);
      ks[i*4+2] = b2f(t.z); ks[i*4+3] = b2f(t.w);
    }
  }
  __syncthreads();

  const int r = threadIdx.x;
  if (r < NN) {
    float qr[DD];
    {
      const ushort4* q4 = (const ushort4*)(q + (size_t)r * DD);
      #pragma unroll
      for (int j = 0; j < 16; j++) {
        ushort4 t = q4[j];
        qr[j*4+0] = b2f(t.x); qr[j*4+1] = b2f(t.y);
        qr[j*4+2] = b2f(t.z); qr[j*4+3] = b2f(t.w);
      }
    }
    float mx = -1e30f;
    for (int m = 0; m < NN; m++) {
      const float4* kp = (const float4*)(ks + m * DD);
      float s = 0.f;
      #pragma unroll
      for (int j4 = 0; j4 < 16; j4++) {
        float4 kk = kp[j4];
        s += qr[j4*4+0]*kk.x + qr[j4*4+1]*kk.y + qr[j4*4+2]*kk.z + qr[j4*4+3]*kk.w;
      }
      mx = fmaxf(mx, s * SCALE_F);
    }
    float o[DD];
    #pragma unroll
    for (int j = 0; j < DD; j++) o[j] = 0.f;
    float sum = 0.f;
    for (int m = 0; m < NN; m++) {
      const float4* kp = (const float4*)(ks + m * DD);
      float s = 0.f;
      #pragma unroll
      for (int j4 = 0; j4 < 16; j4++) {
        float4 kk = kp[j4];
        s += qr[j4*4+0]*kk.x + qr[j4*4+1]*kk.y + qr[j4*4+2]*kk.z + qr[j4*4+3]*kk.w;
      }
      float p = __expf(s * SCALE_F - mx);
      sum += p;
      const ushort4* vp = (const ushort4*)(v + (size_t)m * DD);
      #pragma unroll
      for (int j4 = 0; j4 < 16; j4++) {
        ushort4 vv = vp[j4];
        o[j4*4+0] += p * b2f(vv.x); o[j4*4+1] += p * b2f(vv.y);
        o[j4*4+2] += p * b2f(vv.z); o[j4*4+3] += p * b2f(vv.w);
      }
    }
    const float inv = 1.0f / sum;
    unsigned short* yp = Yc + ((size_t)bb * NN + r) * CC + h * DD;
    #pragma unroll
    for (int j = 0; j < DD; j++) yp[j] = f2b(o[j] * inv);
  }
}

// ---------------------------------------------------------------------------
// Top-k path, fp32-exact, parallel. T1: qc[b][i] = x[b,0,:] . Wq[i,:]
// grid (BB, 12); 4 waves split K, LDS reduce.
// ---------------------------------------------------------------------------
__global__ __launch_bounds__(256, 4) void qcls_kernel(
    const void* __restrict__ x, const void* __restrict__ qkv_w,
    float* __restrict__ qc, const int* __restrict__ flag) {
  const int b = blockIdx.x;
  const int f32 = *flag;
  __shared__ float x0[CC];
  __shared__ float red[4][64];
  const size_t xb0 = (size_t)b * NN * CC;
  for (int i = threadIdx.x; i < CC; i += 256) x0[i] = ldmix(x, xb0 + i, f32);
  __syncthreads();

  const int il = threadIdx.x & 63;           // output within 64-col chunk
  const int part = threadIdx.x >> 6;         // K quarter
  const int i = blockIdx.y * 64 + il;        // Wq row
  const size_t ro = (size_t)i * CC + part * 192;
  float s = 0.f;
  #pragma unroll 8
  for (int c = 0; c < 192; c++) s += x0[part * 192 + c] * ldmix(qkv_w, ro + c, f32);
  red[part][il] = s;
  __syncthreads();
  if (part == 0)
    qc[(size_t)b * CC + i] = red[0][il] + red[1][il] + red[2][il] + red[3][il];
}

// T2: g[b][h][c] = sum_d Wk[768 + h*64 + d][c] * qc[b][h*64+d]; grid (BB, HH)
__global__ __launch_bounds__(256, 4) void gmat_kernel(
    const void* __restrict__ qkv_w, const float* __restrict__ qc,
    float* __restrict__ g, const int* __restrict__ flag) {
  const int b = blockIdx.x, h = blockIdx.y;
  const int f32 = *flag;
  __shared__ float qh[DD];
  if (threadIdx.x < DD) qh[threadIdx.x] = qc[(size_t)b * CC + h * DD + threadIdx.x];
  __syncthreads();
  const int c0 = threadIdx.x, c1 = c0 + 256, c2 = c1 + 512 - 256;
  float a0 = 0.f, a1 = 0.f, a2 = 0.f;
  for (int d = 0; d < DD; d++) {
    const size_t ro = (size_t)(CC + h * DD + d) * CC;
    const float qv = qh[d];
    a0 += ldmix(qkv_w, ro + c0, f32) * qv;
    a1 += ldmix(qkv_w, ro + c1, f32) * qv;
    a2 += ldmix(qkv_w, ro + c2, f32) * qv;
  }
  float* gb = g + ((size_t)b * HH + h) * CC;
  gb[c0] = a0; gb[c1] = a1; gb[c2] = a2;
}

// T3: w[b][n] = sum_h |x[b,n,:] . g[b,h,:]| ; one wave per (b,n)
__global__ __launch_bounds__(256, 4) void score_kernel(
    const void* __restrict__ x, const float* __restrict__ g,
    float* __restrict__ wscore, const int* __restrict__ flag) {
  const int idx = blockIdx.x * 4 + (threadIdx.x >> 6);
  if (idx >= BB * NN) return;
  const int b = idx / NN, n = idx - b * NN;
  const int lane = threadIdx.x & 63;
  const int f32 = *flag;
  const size_t xr = ((size_t)b * NN + n) * CC;
  float xv[12];
  #pragma unroll
  for (int j = 0; j < 12; j++) xv[j] = ldmix(x, xr + j * 64 + lane, f32);
  const float* gb = g + (size_t)b * HH * CC;
  float acc = 0.f;
  #pragma unroll
  for (int h = 0; h < HH; h++) {
    const float* gh = gb + (size_t)h * CC;
    float p = 0.f;
    #pragma unroll
    for (int j = 0; j < 12; j++) p += xv[j] * gh[j * 64 + lane];
    #pragma unroll
    for (int m = 32; m; m >>= 1) p += __shfl_xor(p, m, 64);
    acc += fabsf(p);
  }
  if (lane == 0) wscore[(size_t)b * NN + n] = acc;
}

// T4: per-batch stable rank -> sorted kept indices
__global__ __launch_bounds__(256, 4) void rank_kernel(
    const float* __restrict__ wscore, void* __restrict__ out,
    const int* __restrict__ flag) {
  const int b = blockIdx.x;
  const int f32 = *flag;
  __shared__ float wgt[NN];
  __shared__ int   rank[NN];
  if (threadIdx.x < NN) wgt[threadIdx.x] = wscore[(size_t)b * NN + threadIdx.x];
  __syncthreads();
  const int n = threadIdx.x;
  if (n < NN) {
    float wi = wgt[n];
    int rk = 0;
    for (int j = 0; j < NN; j++) {
      float wj = wgt[j];
      rk += (wj > wi) || (wj == wi && j < n);   // stable top_k tie-break
    }
    rank[n] = rk;
  }
  __syncthreads();
  if (n < NN && rank[n] < KEEP) {
    int pos = 0;
    for (int j = 0; j < n; j++) pos += (rank[j] < KEEP);
    const size_t oi = OUT0_ELEMS + (size_t)b * KEEP + pos;
    if (f32) ((float*)out)[oi] = (float)n;
    else ((unsigned short*)out)[oi] = f2b((float)n);
  }
}

// ---------------------------------------------------------------------------
// out_chunk = Yc @ pw.T + pbf ; dual-dtype store.
// ---------------------------------------------------------------------------
__global__ __launch_bounds__(256, 4) void proj_gemm(
    const unsigned short* __restrict__ Yc,
    const unsigned short* __restrict__ pw,
    const float* __restrict__ pbf,
    void* __restrict__ out, size_t out_elem_off, int Mc,
    const int* __restrict__ flag) {
  const int wave = threadIdx.x >> 6;
  const int lane = threadIdx.x & 63;
  const int l16  = lane & 15;
  const int quad = lane >> 4;
  const int m_base = blockIdx.x * 16;
  const int c_base = blockIdx.y * 64 + wave * 16;

  int row = m_base + l16; if (row >= Mc) row = Mc - 1;
  const short* yp = (const short*)Yc + (size_t)row * CC + quad * 8;
  const short* wp = (const short*)pw + (size_t)(c_base + l16) * CC + quad * 8;

  f32x4_t acc = {0.f, 0.f, 0.f, 0.f};
  #pragma unroll 4
  for (int k = 0; k < CC; k += 32) {
    bf16x8_t a  = *(const bf16x8_t*)(yp + k);
    bf16x8_t bf = *(const bf16x8_t*)(wp + k);
    acc = __builtin_amdgcn_mfma_f32_16x16x32_bf16(a, bf, acc, 0, 0, 0);
  }

  const int c = c_base + l16;
  const float bv = pbf[c];
  const int f32 = *flag;
  #pragma unroll
  for (int i = 0; i < 4; i++) {
    int m = m_base + quad * 4 + i;
    if (m < Mc) {
      float val = acc[i] + bv;
      size_t oi = out_elem_off + (size_t)m * CC + c;
      if (f32) ((float*)out)[oi] = val;
      else ((unsigned short*)out)[oi] = f2b(val);
    }
  }
}

// ---------------------------------------------------------------------------
extern "C" void kernel_launch(void* const* d_in, const int* in_sizes, int n_in,
                              void* d_out, int out_size, void* d_ws, size_t ws_size,
                              hipStream_t stream) {
  const void* x      = d_in[0];
  const void* qkv_w  = d_in[1];
  const void* proj_w = d_in[2];
  const void* proj_b = d_in[3];

  // ws layout (bytes, fixed region):
  //   flag 256 | wb 3,538,944 | pw 1,179,648 | pbf 4,096
  //   qc 196,608 | g 2,359,296 | wscore 50,432 -> pad to 51,200
  char* wsb = (char*)d_ws;
  int* flag = (int*)wsb;
  unsigned short* wb  = (unsigned short*)(wsb + 256);
  unsigned short* pw  = (unsigned short*)(wsb + 256 + 3538944);
  float* pbf    = (float*)(wsb + 256 + 3538944 + 1179648);
  float* qc     = (float*)(wsb + 256 + 3538944 + 1179648 + 4096);
  float* g      = qc + (size_t)BB * CC;
  float* wscore = g + (size_t)BB * HH * CC;
  const size_t fixed = 256 + 3538944 + 1179648 + 4096 + 196608 + 2359296 + 51200;
  char* chunk = wsb + fixed;

  const size_t per_batch = (size_t)NN * CC * 2      // xb_c
                         + 3ull * HH * NN * DD * 2  // qkvc
                         + (size_t)NN * CC * 2;     // Yc  = 1,512,960
  int Bc = BB;
  while (Bc > 1 && fixed + (size_t)Bc * per_batch > ws_size) Bc >>= 1;

  unsigned short* xb   = (unsigned short*)chunk;
  unsigned short* qkvc = xb + (size_t)Bc * NN * CC;
  unsigned short* Yc   = qkvc + 3ull * Bc * HH * NN * DD;

  detect_kernel<<<1, 256, 0, stream>>>(x, flag);
  cvt_bf16<<<(3 * CC * CC + 255) / 256, 256, 0, stream>>>(qkv_w, 0, wb, 3 * CC * CC, flag);
  cvt_bf16<<<(CC * CC + 255) / 256, 256, 0, stream>>>(proj_w, 0, pw, CC * CC, flag);
  cvt_f32<<<(CC + 255) / 256, 256, 0, stream>>>(proj_b, pbf, CC, flag);

  // top-k path (fp32-exact, independent of the bf16 pipeline)
  qcls_kernel<<<dim3(BB, 12), 256, 0, stream>>>(x, qkv_w, qc, flag);
  gmat_kernel<<<dim3(BB, HH), 256, 0, stream>>>(qkv_w, qc, g, flag);
  score_kernel<<<(BB * NN + 3) / 4, 256, 0, stream>>>(x, g, wscore, flag);
  rank_kernel<<<BB, 256, 0, stream>>>(wscore, d_out, flag);

  const int nChunks = (BB + Bc - 1) / Bc;
  for (int cb = 0; cb < nChunks; cb++) {
    const int b0 = cb * Bc;
    const int bc = (BB - b0 < Bc) ? (BB - b0) : Bc;
    const int Mc = bc * NN;
    cvt_bf16<<<(Mc * CC + 255) / 256, 256, 0, stream>>>(
        x, (size_t)b0 * NN * CC, xb, Mc * CC, flag);
    qkv_gemm<<<dim3((Mc + 15) / 16, 36), 256, 0, stream>>>(xb, wb, qkvc, Mc, bc);
    attn_kernel<<<dim3(bc * HH), 256, 0, stream>>>(qkvc, bc, Yc);
    proj_gemm<<<dim3((Mc + 15) / 16, 12), 256, 0, stream>>>(
        Yc, pw, pbf, d_out, (size_t)b0 * NN * CC, Mc, flag);
  }
}

// Round 5
// 883.114 us; speedup vs baseline: 3.0055x; 1.7340x over previous
//
#include <hip/hip_runtime.h>
#include <hip/hip_bf16.h>

// PoolingAttention: B=64 N=197 C=768 H=12 D=64. fp32 in/out (runtime-detected).
// out = [B*N*C] attention output ++ [B*160] keep_index.
//
// R5: both GEMMs rewritten as 128x128 LDS-staged MFMA kernels (BK=32,
// 4 waves x 64x64 output, 16 MFMA + 8 ds_read_b128 per wave per K-step).
// Replaces the un-staged per-wave 16x16 GEMM that ran at MfmaUtil=3% with
// 13x HBM over-fetch (608 us for 44.6 GFLOP).

#define BB 64
#define NN 197
#define CC 768
#define HH 12
#define DD 64
#define KEEP 160
#define SCALE_F 0.125f   // 64^-0.5
#define OUT0_ELEMS ((size_t)BB * NN * CC)   // 9,682,944

typedef __attribute__((ext_vector_type(8))) short bf16x8_t;
typedef __attribute__((ext_vector_type(4))) float f32x4_t;

__device__ __forceinline__ float b2f(unsigned short u) {
  union { unsigned u; float f; } cv; cv.u = (unsigned)u << 16; return cv.f;
}
__device__ __forceinline__ unsigned short f2b(float f) {   // RNE, finite
  union { float f; unsigned u; } cv; cv.f = f;
  return (unsigned short)((cv.u + 0x7FFFu + ((cv.u >> 16) & 1u)) >> 16);
}
__device__ __forceinline__ float ldmix(const void* p, size_t i, int f32) {
  return f32 ? ((const float*)p)[i] : b2f(((const unsigned short*)p)[i]);
}

// ---------------------------------------------------------------------------
__global__ void detect_kernel(const void* x, int* flag) {
  __shared__ int cnt;
  if (threadIdx.x == 0) cnt = 0;
  __syncthreads();
  const unsigned short* u = (const unsigned short*)x;
  int wild = 0;
  for (int i = threadIdx.x; i < 4096; i += 256) {
    int e = (u[i] >> 7) & 0xFF;
    wild += (e >= 140);
  }
  atomicAdd(&cnt, wild);
  __syncthreads();
  if (threadIdx.x == 0) *flag = (cnt > 100) ? 1 : 0;
}

__global__ void cvt_bf16(const void* src, size_t elem_off,
                         unsigned short* dst, int n, const int* flag) {
  int i = blockIdx.x * 256 + threadIdx.x;
  if (i >= n) return;
  const int f32 = *flag;
  if (f32) dst[i] = f2b(((const float*)src)[elem_off + i]);
  else     dst[i] = ((const unsigned short*)src)[elem_off + i];
}
__global__ void cvt_f32(const void* src, float* dst, int n, const int* flag) {
  int i = blockIdx.x * 256 + threadIdx.x;
  if (i >= n) return;
  dst[i] = ldmix(src, i, *flag);
}

// ---------------------------------------------------------------------------
// Shared GEMM mainloop macro: C[128x128] tile at (m0,n0) of A[Mc x 768] @
// Wt[Ncols x 768]^T, both bf16 row-major K-contig. 4 waves in 2x2; wave
// (wm,wn) owns 64x64; acc[r][c] is 16x16 at rows r*16, cols c*16.
// LDS: As/Bs [8 subtiles][16 rows][32 k] bf16, 8 KB each.
// ---------------------------------------------------------------------------
#define GEMM_MAINLOOP(APTR, BPTR)                                             \
  __shared__ unsigned short As[4096];                                         \
  __shared__ unsigned short Bs[4096];                                         \
  const int lane = threadIdx.x & 63;                                          \
  const int wave = threadIdx.x >> 6;                                          \
  const int l16  = lane & 15;                                                 \
  const int quad = lane >> 4;                                                 \
  const int wm = wave >> 1, wn = wave & 1;                                    \
  const int m0 = blockIdx.x * 128;                                            \
  const int n0 = blockIdx.y * 128;                                            \
  f32x4_t acc[4][4] = {};                                                     \
  for (int kt = 0; kt < 24; kt++) {                                           \
    const int k0 = kt * 32;                                                   \
    __syncthreads();                                                          \
    _Pragma("unroll")                                                         \
    for (int ch = threadIdx.x; ch < 512; ch += 256) {                         \
      int row = ch >> 2, kg = ch & 3;                                         \
      int gr = m0 + row; if (gr >= Mc) gr = Mc - 1;                           \
      *(bf16x8_t*)&As[(row >> 4) * 512 + (row & 15) * 32 + kg * 8] =          \
          *(const bf16x8_t*)(APTR + (size_t)gr * CC + k0 + kg * 8);           \
    }                                                                         \
    _Pragma("unroll")                                                         \
    for (int ch = threadIdx.x; ch < 512; ch += 256) {                         \
      int row = ch >> 2, kg = ch & 3;                                         \
      *(bf16x8_t*)&Bs[(row >> 4) * 512 + (row & 15) * 32 + kg * 8] =          \
          *(const bf16x8_t*)(BPTR + (size_t)(n0 + row) * CC + k0 + kg * 8);   \
    }                                                                         \
    __syncthreads();                                                          \
    bf16x8_t afr[4], bfr[4];                                                  \
    _Pragma("unroll")                                                         \
    for (int r = 0; r < 4; r++)                                               \
      afr[r] = *(const bf16x8_t*)&As[(wm * 4 + r) * 512 + l16 * 32 + quad * 8];\
    _Pragma("unroll")                                                         \
    for (int c = 0; c < 4; c++)                                               \
      bfr[c] = *(const bf16x8_t*)&Bs[(wn * 4 + c) * 512 + l16 * 32 + quad * 8];\
    _Pragma("unroll")                                                         \
    for (int r = 0; r < 4; r++)                                               \
      _Pragma("unroll")                                                       \
      for (int c = 0; c < 4; c++)                                             \
        acc[r][c] =                                                           \
            __builtin_amdgcn_mfma_f32_16x16x32_bf16(afr[r], bfr[c], acc[r][c],\
                                                    0, 0, 0);                 \
  }

// qkvc[s][bb][h][n][d] = (x @ qkv_w.T), bf16. Ncols = 2304 (18 col-tiles).
__global__ __launch_bounds__(256, 2) void qkv_gemm(
    const unsigned short* __restrict__ xb,
    const unsigned short* __restrict__ wb,
    unsigned short* __restrict__ qkvc, int Mc, int bc) {
  GEMM_MAINLOOP(xb, wb)
  #pragma unroll
  for (int c = 0; c < 4; c++) {
    const int col = n0 + wn * 64 + c * 16 + l16;
    const int s = col / CC;
    const int rem = col - s * CC;
    const int hc = rem >> 6, d = rem & 63;
    #pragma unroll
    for (int r = 0; r < 4; r++) {
      #pragma unroll
      for (int i = 0; i < 4; i++) {
        const int m = m0 + wm * 64 + r * 16 + quad * 4 + i;
        if (m < Mc) {
          const int bb = m / NN, n = m - bb * NN;
          qkvc[((((size_t)s * bc + bb) * HH + hc) * NN + n) * DD + d] =
              f2b(acc[r][c][i]);
        }
      }
    }
  }
}

// out = Yc @ proj_w.T + bias; Ncols = 768 (6 col-tiles); dual-dtype store.
__global__ __launch_bounds__(256, 2) void proj_gemm(
    const unsigned short* __restrict__ Yc,
    const unsigned short* __restrict__ pw,
    const float* __restrict__ pbf,
    void* __restrict__ out, size_t out_off, int Mc,
    const int* __restrict__ flag) {
  GEMM_MAINLOOP(Yc, pw)
  const int f32 = *flag;
  #pragma unroll
  for (int c = 0; c < 4; c++) {
    const int col = n0 + wn * 64 + c * 16 + l16;
    const float bv = pbf[col];
    #pragma unroll
    for (int r = 0; r < 4; r++) {
      #pragma unroll
      for (int i = 0; i < 4; i++) {
        const int m = m0 + wm * 64 + r * 16 + quad * 4 + i;
        if (m < Mc) {
          const float val = acc[r][c][i] + bv;
          const size_t oi = out_off + (size_t)m * CC + col;
          if (f32) ((float*)out)[oi] = val;
          else ((unsigned short*)out)[oi] = f2b(val);
        }
      }
    }
  }
}

// ---------------------------------------------------------------------------
// per (bb,h) attention; K fp32 in LDS; 1 thread/query; 2-pass softmax fp32.
// Dot products use 8 independent accumulators (dependent-FMA chain 256->32cy).
// ---------------------------------------------------------------------------
__global__ __launch_bounds__(256, 1) void attn_kernel(
    const unsigned short* __restrict__ qkvc, int bc,
    unsigned short* __restrict__ Yc) {
  const int bh = blockIdx.x;
  const int bb = bh / HH;
  const int h  = bh % HH;
  const size_t mat = (size_t)bc * HH * NN * DD;
  const unsigned short* q = qkvc + ((size_t)bb * HH + h) * NN * DD;
  const unsigned short* k = q + mat;
  const unsigned short* v = q + 2 * mat;

  __shared__ float ks[NN * DD];  // 50,432 B
  {
    const ushort4* k4 = (const ushort4*)k;
    for (int i = threadIdx.x; i < NN * DD / 4; i += 256) {
      ushort4 t = k4[i];
      ks[i*4+0] = b2f(t.x); ks[i*4+1] = b2f(t.y);
      ks[i*4+2] = b2f(t.z); ks[i*4+3] = b2f(t.w);
    }
  }
  __syncthreads();

  const int r = threadIdx.x;
  if (r < NN) {
    float qr[DD];
    {
      const ushort4* q4 = (const ushort4*)(q + (size_t)r * DD);
      #pragma unroll
      for (int j = 0; j < 16; j++) {
        ushort4 t = q4[j];
        qr[j*4+0] = b2f(t.x); qr[j*4+1] = b2f(t.y);
        qr[j*4+2] = b2f(t.z); qr[j*4+3] = b2f(t.w);
      }
    }
    float mx = -1e30f;
    for (int m = 0; m < NN; m++) {
      const float4* kp = (const float4*)(ks + m * DD);
      float sa[8] = {0,0,0,0,0,0,0,0};
      #pragma unroll
      for (int j4 = 0; j4 < 16; j4++) {
        float4 kk = kp[j4];
        sa[(j4&1)*4+0] += qr[j4*4+0]*kk.x; sa[(j4&1)*4+1] += qr[j4*4+1]*kk.y;
        sa[(j4&1)*4+2] += qr[j4*4+2]*kk.z; sa[(j4&1)*4+3] += qr[j4*4+3]*kk.w;
      }
      float s = ((sa[0]+sa[1])+(sa[2]+sa[3])) + ((sa[4]+sa[5])+(sa[6]+sa[7]));
      mx = fmaxf(mx, s * SCALE_F);
    }
    float o[DD];
    #pragma unroll
    for (int j = 0; j < DD; j++) o[j] = 0.f;
    float sum = 0.f;
    for (int m = 0; m < NN; m++) {
      const float4* kp = (const float4*)(ks + m * DD);
      float sa[8] = {0,0,0,0,0,0,0,0};
      #pragma unroll
      for (int j4 = 0; j4 < 16; j4++) {
        float4 kk = kp[j4];
        sa[(j4&1)*4+0] += qr[j4*4+0]*kk.x; sa[(j4&1)*4+1] += qr[j4*4+1]*kk.y;
        sa[(j4&1)*4+2] += qr[j4*4+2]*kk.z; sa[(j4&1)*4+3] += qr[j4*4+3]*kk.w;
      }
      float s = ((sa[0]+sa[1])+(sa[2]+sa[3])) + ((sa[4]+sa[5])+(sa[6]+sa[7]));
      float p = __expf(s * SCALE_F - mx);
      sum += p;
      const ushort4* vp = (const ushort4*)(v + (size_t)m * DD);
      #pragma unroll
      for (int j4 = 0; j4 < 16; j4++) {
        ushort4 vv = vp[j4];
        o[j4*4+0] += p * b2f(vv.x); o[j4*4+1] += p * b2f(vv.y);
        o[j4*4+2] += p * b2f(vv.z); o[j4*4+3] += p * b2f(vv.w);
      }
    }
    const float inv = 1.0f / sum;
    unsigned short* yp = Yc + ((size_t)bb * NN + r) * CC + h * DD;
    #pragma unroll
    for (int j = 0; j < DD; j++) yp[j] = f2b(o[j] * inv);
  }
}

// ---------------------------------------------------------------------------
// Top-k path, fp32-exact (matches np reference bit-for-bit in ranking).
// ---------------------------------------------------------------------------
__global__ __launch_bounds__(256, 4) void qcls_kernel(
    const void* __restrict__ x, const void* __restrict__ qkv_w,
    float* __restrict__ qc, const int* __restrict__ flag) {
  const int b = blockIdx.x;
  const int f32 = *flag;
  __shared__ float x0[CC];
  __shared__ float red[4][64];
  const size_t xb0 = (size_t)b * NN * CC;
  for (int i = threadIdx.x; i < CC; i += 256) x0[i] = ldmix(x, xb0 + i, f32);
  __syncthreads();

  const int il = threadIdx.x & 63;
  const int part = threadIdx.x >> 6;
  const int i = blockIdx.y * 64 + il;
  const size_t ro = (size_t)i * CC + part * 192;
  float s = 0.f;
  #pragma unroll 8
  for (int c = 0; c < 192; c++) s += x0[part * 192 + c] * ldmix(qkv_w, ro + c, f32);
  red[part][il] = s;
  __syncthreads();
  if (part == 0)
    qc[(size_t)b * CC + i] = red[0][il] + red[1][il] + red[2][il] + red[3][il];
}

__global__ __launch_bounds__(256, 4) void gmat_kernel(
    const void* __restrict__ qkv_w, const float* __restrict__ qc,
    float* __restrict__ g, const int* __restrict__ flag) {
  const int b = blockIdx.x, h = blockIdx.y;
  const int f32 = *flag;
  __shared__ float qh[DD];
  if (threadIdx.x < DD) qh[threadIdx.x] = qc[(size_t)b * CC + h * DD + threadIdx.x];
  __syncthreads();
  const int c0 = threadIdx.x, c1 = c0 + 256, c2 = c1 + 256;
  float a0 = 0.f, a1 = 0.f, a2 = 0.f;
  for (int d = 0; d < DD; d++) {
    const size_t ro = (size_t)(CC + h * DD + d) * CC;
    const float qv = qh[d];
    a0 += ldmix(qkv_w, ro + c0, f32) * qv;
    a1 += ldmix(qkv_w, ro + c1, f32) * qv;
    a2 += ldmix(qkv_w, ro + c2, f32) * qv;
  }
  float* gb = g + ((size_t)b * HH + h) * CC;
  gb[c0] = a0; gb[c1] = a1; gb[c2] = a2;
}

__global__ __launch_bounds__(256, 4) void score_kernel(
    const void* __restrict__ x, const float* __restrict__ g,
    float* __restrict__ wscore, const int* __restrict__ flag) {
  const int idx = blockIdx.x * 4 + (threadIdx.x >> 6);
  if (idx >= BB * NN) return;
  const int b = idx / NN, n = idx - b * NN;
  const int lane = threadIdx.x & 63;
  const int f32 = *flag;
  const size_t xr = ((size_t)b * NN + n) * CC;
  float xv[12];
  #pragma unroll
  for (int j = 0; j < 12; j++) xv[j] = ldmix(x, xr + j * 64 + lane, f32);
  const float* gb = g + (size_t)b * HH * CC;
  float acc = 0.f;
  #pragma unroll
  for (int h = 0; h < HH; h++) {
    const float* gh = gb + (size_t)h * CC;
    float p = 0.f;
    #pragma unroll
    for (int j = 0; j < 12; j++) p += xv[j] * gh[j * 64 + lane];
    #pragma unroll
    for (int m = 32; m; m >>= 1) p += __shfl_xor(p, m, 64);
    acc += fabsf(p);
  }
  if (lane == 0) wscore[(size_t)b * NN + n] = acc;
}

__global__ __launch_bounds__(256, 4) void rank_kernel(
    const float* __restrict__ wscore, void* __restrict__ out,
    const int* __restrict__ flag) {
  const int b = blockIdx.x;
  const int f32 = *flag;
  __shared__ float wgt[NN];
  __shared__ int   rank[NN];
  if (threadIdx.x < NN) wgt[threadIdx.x] = wscore[(size_t)b * NN + threadIdx.x];
  __syncthreads();
  const int n = threadIdx.x;
  if (n < NN) {
    float wi = wgt[n];
    int rk = 0;
    for (int j = 0; j < NN; j++) {
      float wj = wgt[j];
      rk += (wj > wi) || (wj == wi && j < n);   // stable top_k tie-break
    }
    rank[n] = rk;
  }
  __syncthreads();
  if (n < NN && rank[n] < KEEP) {
    int pos = 0;
    for (int j = 0; j < n; j++) pos += (rank[j] < KEEP);
    const size_t oi = OUT0_ELEMS + (size_t)b * KEEP + pos;
    if (f32) ((float*)out)[oi] = (float)n;
    else ((unsigned short*)out)[oi] = f2b((float)n);
  }
}

// ---------------------------------------------------------------------------
extern "C" void kernel_launch(void* const* d_in, const int* in_sizes, int n_in,
                              void* d_out, int out_size, void* d_ws, size_t ws_size,
                              hipStream_t stream) {
  const void* x      = d_in[0];
  const void* qkv_w  = d_in[1];
  const void* proj_w = d_in[2];
  const void* proj_b = d_in[3];

  char* wsb = (char*)d_ws;
  int* flag = (int*)wsb;
  unsigned short* wb  = (unsigned short*)(wsb + 256);
  unsigned short* pw  = (unsigned short*)(wsb + 256 + 3538944);
  float* pbf    = (float*)(wsb + 256 + 3538944 + 1179648);
  float* qc     = (float*)(wsb + 256 + 3538944 + 1179648 + 4096);
  float* g      = qc + (size_t)BB * CC;
  float* wscore = g + (size_t)BB * HH * CC;
  const size_t fixed = 256 + 3538944 + 1179648 + 4096 + 196608 + 2359296 + 51200;
  char* chunk = wsb + fixed;

  const size_t per_batch = (size_t)NN * CC * 2      // xb_c
                         + 3ull * HH * NN * DD * 2  // qkvc
                         + (size_t)NN * CC * 2;     // Yc  = 1,512,960
  int Bc = BB;
  while (Bc > 1 && fixed + (size_t)Bc * per_batch > ws_size) Bc >>= 1;

  unsigned short* xb   = (unsigned short*)chunk;
  unsigned short* qkvc = xb + (size_t)Bc * NN * CC;
  unsigned short* Yc   = qkvc + 3ull * Bc * HH * NN * DD;

  detect_kernel<<<1, 256, 0, stream>>>(x, flag);
  cvt_bf16<<<(3 * CC * CC + 255) / 256, 256, 0, stream>>>(qkv_w, 0, wb, 3 * CC * CC, flag);
  cvt_bf16<<<(CC * CC + 255) / 256, 256, 0, stream>>>(proj_w, 0, pw, CC * CC, flag);
  cvt_f32<<<(CC + 255) / 256, 256, 0, stream>>>(proj_b, pbf, CC, flag);

  // top-k path (fp32-exact, independent of the bf16 pipeline)
  qcls_kernel<<<dim3(BB, 12), 256, 0, stream>>>(x, qkv_w, qc, flag);
  gmat_kernel<<<dim3(BB, HH), 256, 0, stream>>>(qkv_w, qc, g, flag);
  score_kernel<<<(BB * NN + 3) / 4, 256, 0, stream>>>(x, g, wscore, flag);
  rank_kernel<<<BB, 256, 0, stream>>>(wscore, d_out, flag);

  const int nChunks = (BB + Bc - 1) / Bc;
  for (int cb = 0; cb < nChunks; cb++) {
    const int b0 = cb * Bc;
    const int bc = (BB - b0 < Bc) ? (BB - b0) : Bc;
    const int Mc = bc * NN;
    cvt_bf16<<<(Mc * CC + 255) / 256, 256, 0, stream>>>(
        x, (size_t)b0 * NN * CC, xb, Mc * CC, flag);
    qkv_gemm<<<dim3((Mc + 127) / 128, 18), 256, 0, stream>>>(xb, wb, qkvc, Mc, bc);
    attn_kernel<<<dim3(bc * HH), 256, 0, stream>>>(qkvc, bc, Yc);
    proj_gemm<<<dim3((Mc + 127) / 128, 6), 256, 0, stream>>>(
        Yc, pw, pbf, d_out, (size_t)b0 * NN * CC, Mc, flag);
  }
}

// Round 6
// 576.121 us; speedup vs baseline: 4.6070x; 1.5329x over previous
//
#include <hip/hip_runtime.h>
#include <hip/hip_bf16.h>

// PoolingAttention: B=64 N=197 C=768 H=12 D=64. fp32 in/out (runtime-detected).
// out = [B*N*C] attention output ++ [B*160] keep_index.
//
// R6: MFMA flash-style attention. Per (b,h,qblock) block: 16x208 score strip
// per wave via 16x16x32 bf16 MFMA (Q/K frags direct from global), register
// softmax with shfl_xor row reduce, P->LDS bf16 (A-layout), V^T staged in LDS
// (stride 232, zero-padded), PV via MFMA. Replaces the scalar-VALU attention
// that ran at MfmaUtil=0 / 468 us.

#define BB 64
#define NN 197
#define CC 768
#define HH 12
#define DD 64
#define KEEP 160
#define SCALE_F 0.125f   // 64^-0.5
#define OUT0_ELEMS ((size_t)BB * NN * CC)   // 9,682,944
#define VST 232          // LDS row stride (elems) for Vt/P: 16B-aligned, non-pow2

typedef __attribute__((ext_vector_type(8))) short bf16x8_t;
typedef __attribute__((ext_vector_type(4))) float f32x4_t;

__device__ __forceinline__ float b2f(unsigned short u) {
  union { unsigned u; float f; } cv; cv.u = (unsigned)u << 16; return cv.f;
}
__device__ __forceinline__ unsigned short f2b(float f) {   // RNE, finite
  union { float f; unsigned u; } cv; cv.f = f;
  return (unsigned short)((cv.u + 0x7FFFu + ((cv.u >> 16) & 1u)) >> 16);
}
__device__ __forceinline__ float ldmix(const void* p, size_t i, int f32) {
  return f32 ? ((const float*)p)[i] : b2f(((const unsigned short*)p)[i]);
}

// ---------------------------------------------------------------------------
__global__ void detect_kernel(const void* x, int* flag) {
  __shared__ int cnt;
  if (threadIdx.x == 0) cnt = 0;
  __syncthreads();
  const unsigned short* u = (const unsigned short*)x;
  int wild = 0;
  for (int i = threadIdx.x; i < 4096; i += 256) {
    int e = (u[i] >> 7) & 0xFF;
    wild += (e >= 140);
  }
  atomicAdd(&cnt, wild);
  __syncthreads();
  if (threadIdx.x == 0) *flag = (cnt > 100) ? 1 : 0;
}

__global__ void cvt_bf16(const void* src, size_t elem_off,
                         unsigned short* dst, int n, const int* flag) {
  int i = blockIdx.x * 256 + threadIdx.x;
  if (i >= n) return;
  const int f32 = *flag;
  if (f32) dst[i] = f2b(((const float*)src)[elem_off + i]);
  else     dst[i] = ((const unsigned short*)src)[elem_off + i];
}
__global__ void cvt_f32(const void* src, float* dst, int n, const int* flag) {
  int i = blockIdx.x * 256 + threadIdx.x;
  if (i >= n) return;
  dst[i] = ldmix(src, i, *flag);
}

// ---------------------------------------------------------------------------
// 128x128 LDS-staged GEMM mainloop (unchanged from R5): A[Mc x 768] @ W^T.
// ---------------------------------------------------------------------------
#define GEMM_MAINLOOP(APTR, BPTR)                                             \
  __shared__ unsigned short As[4096];                                         \
  __shared__ unsigned short Bs[4096];                                         \
  const int lane = threadIdx.x & 63;                                          \
  const int wave = threadIdx.x >> 6;                                          \
  const int l16  = lane & 15;                                                 \
  const int quad = lane >> 4;                                                 \
  const int wm = wave >> 1, wn = wave & 1;                                    \
  const int m0 = blockIdx.x * 128;                                            \
  const int n0 = blockIdx.y * 128;                                            \
  f32x4_t acc[4][4] = {};                                                     \
  for (int kt = 0; kt < 24; kt++) {                                           \
    const int k0 = kt * 32;                                                   \
    __syncthreads();                                                          \
    _Pragma("unroll")                                                         \
    for (int ch = threadIdx.x; ch < 512; ch += 256) {                         \
      int row = ch >> 2, kg = ch & 3;                                         \
      int gr = m0 + row; if (gr >= Mc) gr = Mc - 1;                           \
      *(bf16x8_t*)&As[(row >> 4) * 512 + (row & 15) * 32 + kg * 8] =          \
          *(const bf16x8_t*)(APTR + (size_t)gr * CC + k0 + kg * 8);           \
    }                                                                         \
    _Pragma("unroll")                                                         \
    for (int ch = threadIdx.x; ch < 512; ch += 256) {                         \
      int row = ch >> 2, kg = ch & 3;                                         \
      *(bf16x8_t*)&Bs[(row >> 4) * 512 + (row & 15) * 32 + kg * 8] =          \
          *(const bf16x8_t*)(BPTR + (size_t)(n0 + row) * CC + k0 + kg * 8);   \
    }                                                                         \
    __syncthreads();                                                          \
    bf16x8_t afr[4], bfr[4];                                                  \
    _Pragma("unroll")                                                         \
    for (int r = 0; r < 4; r++)                                               \
      afr[r] = *(const bf16x8_t*)&As[(wm * 4 + r) * 512 + l16 * 32 + quad * 8];\
    _Pragma("unroll")                                                         \
    for (int c = 0; c < 4; c++)                                               \
      bfr[c] = *(const bf16x8_t*)&Bs[(wn * 4 + c) * 512 + l16 * 32 + quad * 8];\
    _Pragma("unroll")                                                         \
    for (int r = 0; r < 4; r++)                                               \
      _Pragma("unroll")                                                       \
      for (int c = 0; c < 4; c++)                                             \
        acc[r][c] =                                                           \
            __builtin_amdgcn_mfma_f32_16x16x32_bf16(afr[r], bfr[c], acc[r][c],\
                                                    0, 0, 0);                 \
  }

__global__ __launch_bounds__(256, 2) void qkv_gemm(
    const unsigned short* __restrict__ xb,
    const unsigned short* __restrict__ wb,
    unsigned short* __restrict__ qkvc, int Mc, int bc) {
  GEMM_MAINLOOP(xb, wb)
  #pragma unroll
  for (int c = 0; c < 4; c++) {
    const int col = n0 + wn * 64 + c * 16 + l16;
    const int s = col / CC;
    const int rem = col - s * CC;
    const int hc = rem >> 6, d = rem & 63;
    #pragma unroll
    for (int r = 0; r < 4; r++) {
      #pragma unroll
      for (int i = 0; i < 4; i++) {
        const int m = m0 + wm * 64 + r * 16 + quad * 4 + i;
        if (m < Mc) {
          const int bb = m / NN, n = m - bb * NN;
          qkvc[((((size_t)s * bc + bb) * HH + hc) * NN + n) * DD + d] =
              f2b(acc[r][c][i]);
        }
      }
    }
  }
}

__global__ __launch_bounds__(256, 2) void proj_gemm(
    const unsigned short* __restrict__ Yc,
    const unsigned short* __restrict__ pw,
    const float* __restrict__ pbf,
    void* __restrict__ out, size_t out_off, int Mc,
    const int* __restrict__ flag) {
  GEMM_MAINLOOP(Yc, pw)
  const int f32 = *flag;
  #pragma unroll
  for (int c = 0; c < 4; c++) {
    const int col = n0 + wn * 64 + c * 16 + l16;
    const float bv = pbf[col];
    #pragma unroll
    for (int r = 0; r < 4; r++) {
      #pragma unroll
      for (int i = 0; i < 4; i++) {
        const int m = m0 + wm * 64 + r * 16 + quad * 4 + i;
        if (m < Mc) {
          const float val = acc[r][c][i] + bv;
          const size_t oi = out_off + (size_t)m * CC + col;
          if (f32) ((float*)out)[oi] = val;
          else ((unsigned short*)out)[oi] = f2b(val);
        }
      }
    }
  }
}

// ---------------------------------------------------------------------------
// MFMA attention. Grid (bc*HH, 4); block = 4 waves; wave handles 16 q-rows.
// ---------------------------------------------------------------------------
__global__ __launch_bounds__(256, 2) void attn_kernel(
    const unsigned short* __restrict__ qkvc, int bc,
    unsigned short* __restrict__ Yc) {
  const int bh = blockIdx.x;
  const int bb = bh / HH;
  const int h  = bh % HH;
  const int qb = blockIdx.y * 64;
  const size_t mat = (size_t)bc * HH * NN * DD;
  const unsigned short* q = qkvc + ((size_t)bb * HH + h) * NN * DD;
  const unsigned short* k = q + mat;
  const unsigned short* v = q + 2 * mat;

  __shared__ unsigned short Vt[DD * VST];       // 29,696 B  (V^T, zero-padded)
  __shared__ unsigned short Pl[4][16 * VST];    // 29,696 B  (per-wave P strip)

  const int lane = threadIdx.x & 63;
  const int wave = threadIdx.x >> 6;
  const int l16  = lane & 15;
  const int quad = lane >> 4;

  // stage V^T: Vt[d][key], keys 197..223 zeroed. Coalesced 128B global reads.
  #pragma unroll 8
  for (int it = 0; it < 56; it++) {
    const int key = it * 4 + wave;
    unsigned short val = (key < NN) ? v[(size_t)key * DD + lane]
                                    : (unsigned short)0;
    Vt[lane * VST + key] = val;
  }
  __syncthreads();

  // S strip = Q[16 rows] x K^T (26 MFMAs), frags direct from global (L1/L2).
  const int qrow = qb + wave * 16 + l16;
  const unsigned short* qp =
      q + (size_t)(qrow < NN ? qrow : NN - 1) * DD + quad * 8;
  const bf16x8_t aq0 = *(const bf16x8_t*)qp;
  const bf16x8_t aq1 = *(const bf16x8_t*)(qp + 32);

  f32x4_t sc[13];
  #pragma unroll
  for (int ct = 0; ct < 13; ct++) {
    int key = ct * 16 + l16; if (key >= NN) key = NN - 1;
    const unsigned short* kp = k + (size_t)key * DD + quad * 8;
    const bf16x8_t b0 = *(const bf16x8_t*)kp;
    const bf16x8_t b1 = *(const bf16x8_t*)(kp + 32);
    f32x4_t t = {0.f, 0.f, 0.f, 0.f};
    t = __builtin_amdgcn_mfma_f32_16x16x32_bf16(aq0, b0, t, 0, 0, 0);
    t = __builtin_amdgcn_mfma_f32_16x16x32_bf16(aq1, b1, t, 0, 0, 0);
    sc[ct] = t;
  }

  // softmax per row (row = quad*4+i, cols spread over l16 x 13 tiles)
  float inv_l[4];
  #pragma unroll
  for (int i = 0; i < 4; i++) {
    float m = -1e30f;
    #pragma unroll
    for (int ct = 0; ct < 13; ct++)
      if (ct < 12 || l16 < 5) m = fmaxf(m, sc[ct][i] * SCALE_F);
    #pragma unroll
    for (int d = 1; d < 16; d <<= 1) m = fmaxf(m, __shfl_xor(m, d, 64));
    float s = 0.f;
    #pragma unroll
    for (int ct = 0; ct < 13; ct++) {
      const float p = (ct < 12 || l16 < 5) ? __expf(sc[ct][i] * SCALE_F - m)
                                           : 0.f;
      sc[ct][i] = p;
      s += p;
    }
    #pragma unroll
    for (int d = 1; d < 16; d <<= 1) s += __shfl_xor(s, d, 64);
    inv_l[i] = 1.0f / s;
  }

  // P strip -> LDS bf16 in A-operand layout [q_local][key], pad cols zeroed
  unsigned short* Pw = &Pl[wave][0];
  #pragma unroll
  for (int i = 0; i < 4; i++) {
    const int ro = (quad * 4 + i) * VST;
    #pragma unroll
    for (int ct = 0; ct < 13; ct++)
      Pw[ro + ct * 16 + l16] = f2b(sc[ct][i]);
    Pw[ro + 208 + l16] = 0;
  }
  __syncthreads();   // uniform; orders P writes before reads

  // O strip = P(16x224) @ V(224x64): 28 MFMAs
  f32x4_t oc[4] = {};
  #pragma unroll
  for (int ks = 0; ks < 7; ks++) {
    const bf16x8_t ap = *(const bf16x8_t*)&Pw[l16 * VST + ks * 32 + quad * 8];
    #pragma unroll
    for (int dt = 0; dt < 4; dt++) {
      const bf16x8_t bv =
          *(const bf16x8_t*)&Vt[(dt * 16 + l16) * VST + ks * 32 + quad * 8];
      oc[dt] = __builtin_amdgcn_mfma_f32_16x16x32_bf16(ap, bv, oc[dt], 0, 0, 0);
    }
  }

  #pragma unroll
  for (int i = 0; i < 4; i++) {
    const int n = qb + wave * 16 + quad * 4 + i;
    if (n < NN) {
      unsigned short* yp = Yc + ((size_t)bb * NN + n) * CC + h * DD;
      #pragma unroll
      for (int dt = 0; dt < 4; dt++)
        yp[dt * 16 + l16] = f2b(oc[dt][i] * inv_l[i]);
    }
  }
}

// ---------------------------------------------------------------------------
// Top-k path, fp32-exact (matches np reference ranking).
// ---------------------------------------------------------------------------
__global__ __launch_bounds__(256, 4) void qcls_kernel(
    const void* __restrict__ x, const void* __restrict__ qkv_w,
    float* __restrict__ qc, const int* __restrict__ flag) {
  const int b = blockIdx.x;
  const int f32 = *flag;
  __shared__ float x0[CC];
  __shared__ float red[4][64];
  const size_t xb0 = (size_t)b * NN * CC;
  for (int i = threadIdx.x; i < CC; i += 256) x0[i] = ldmix(x, xb0 + i, f32);
  __syncthreads();

  const int il = threadIdx.x & 63;
  const int part = threadIdx.x >> 6;
  const int i = blockIdx.y * 64 + il;
  const size_t ro = (size_t)i * CC + part * 192;
  float s = 0.f;
  #pragma unroll 8
  for (int c = 0; c < 192; c++) s += x0[part * 192 + c] * ldmix(qkv_w, ro + c, f32);
  red[part][il] = s;
  __syncthreads();
  if (part == 0)
    qc[(size_t)b * CC + i] = red[0][il] + red[1][il] + red[2][il] + red[3][il];
}

__global__ __launch_bounds__(256, 4) void gmat_kernel(
    const void* __restrict__ qkv_w, const float* __restrict__ qc,
    float* __restrict__ g, const int* __restrict__ flag) {
  const int b = blockIdx.x, h = blockIdx.y;
  const int f32 = *flag;
  __shared__ float qh[DD];
  if (threadIdx.x < DD) qh[threadIdx.x] = qc[(size_t)b * CC + h * DD + threadIdx.x];
  __syncthreads();
  const int c0 = threadIdx.x, c1 = c0 + 256, c2 = c1 + 256;
  float a0 = 0.f, a1 = 0.f, a2 = 0.f;
  for (int d = 0; d < DD; d++) {
    const size_t ro = (size_t)(CC + h * DD + d) * CC;
    const float qv = qh[d];
    a0 += ldmix(qkv_w, ro + c0, f32) * qv;
    a1 += ldmix(qkv_w, ro + c1, f32) * qv;
    a2 += ldmix(qkv_w, ro + c2, f32) * qv;
  }
  float* gb = g + ((size_t)b * HH + h) * CC;
  gb[c0] = a0; gb[c1] = a1; gb[c2] = a2;
}

__global__ __launch_bounds__(256, 4) void score_kernel(
    const void* __restrict__ x, const float* __restrict__ g,
    float* __restrict__ wscore, const int* __restrict__ flag) {
  const int idx = blockIdx.x * 4 + (threadIdx.x >> 6);
  if (idx >= BB * NN) return;
  const int b = idx / NN, n = idx - b * NN;
  const int lane = threadIdx.x & 63;
  const int f32 = *flag;
  const size_t xr = ((size_t)b * NN + n) * CC;
  float xv[12];
  #pragma unroll
  for (int j = 0; j < 12; j++) xv[j] = ldmix(x, xr + j * 64 + lane, f32);
  const float* gb = g + (size_t)b * HH * CC;
  float acc = 0.f;
  #pragma unroll
  for (int h = 0; h < HH; h++) {
    const float* gh = gb + (size_t)h * CC;
    float p = 0.f;
    #pragma unroll
    for (int j = 0; j < 12; j++) p += xv[j] * gh[j * 64 + lane];
    #pragma unroll
    for (int m = 32; m; m >>= 1) p += __shfl_xor(p, m, 64);
    acc += fabsf(p);
  }
  if (lane == 0) wscore[(size_t)b * NN + n] = acc;
}

__global__ __launch_bounds__(256, 4) void rank_kernel(
    const float* __restrict__ wscore, void* __restrict__ out,
    const int* __restrict__ flag) {
  const int b = blockIdx.x;
  const int f32 = *flag;
  __shared__ float wgt[NN];
  __shared__ int   rank[NN];
  if (threadIdx.x < NN) wgt[threadIdx.x] = wscore[(size_t)b * NN + threadIdx.x];
  __syncthreads();
  const int n = threadIdx.x;
  if (n < NN) {
    float wi = wgt[n];
    int rk = 0;
    for (int j = 0; j < NN; j++) {
      float wj = wgt[j];
      rk += (wj > wi) || (wj == wi && j < n);   // stable top_k tie-break
    }
    rank[n] = rk;
  }
  __syncthreads();
  if (n < NN && rank[n] < KEEP) {
    int pos = 0;
    for (int j = 0; j < n; j++) pos += (rank[j] < KEEP);
    const size_t oi = OUT0_ELEMS + (size_t)b * KEEP + pos;
    if (f32) ((float*)out)[oi] = (float)n;
    else ((unsigned short*)out)[oi] = f2b((float)n);
  }
}

// ---------------------------------------------------------------------------
extern "C" void kernel_launch(void* const* d_in, const int* in_sizes, int n_in,
                              void* d_out, int out_size, void* d_ws, size_t ws_size,
                              hipStream_t stream) {
  const void* x      = d_in[0];
  const void* qkv_w  = d_in[1];
  const void* proj_w = d_in[2];
  const void* proj_b = d_in[3];

  char* wsb = (char*)d_ws;
  int* flag = (int*)wsb;
  unsigned short* wb  = (unsigned short*)(wsb + 256);
  unsigned short* pw  = (unsigned short*)(wsb + 256 + 3538944);
  float* pbf    = (float*)(wsb + 256 + 3538944 + 1179648);
  float* qc     = (float*)(wsb + 256 + 3538944 + 1179648 + 4096);
  float* g      = qc + (size_t)BB * CC;
  float* wscore = g + (size_t)BB * HH * CC;
  const size_t fixed = 256 + 3538944 + 1179648 + 4096 + 196608 + 2359296 + 51200;
  char* chunk = wsb + fixed;

  const size_t per_batch = (size_t)NN * CC * 2      // xb_c
                         + 3ull * HH * NN * DD * 2  // qkvc
                         + (size_t)NN * CC * 2;     // Yc  = 1,512,960
  int Bc = BB;
  while (Bc > 1 && fixed + (size_t)Bc * per_batch > ws_size) Bc >>= 1;

  unsigned short* xb   = (unsigned short*)chunk;
  unsigned short* qkvc = xb + (size_t)Bc * NN * CC;
  unsigned short* Yc   = qkvc + 3ull * Bc * HH * NN * DD;

  detect_kernel<<<1, 256, 0, stream>>>(x, flag);
  cvt_bf16<<<(3 * CC * CC + 255) / 256, 256, 0, stream>>>(qkv_w, 0, wb, 3 * CC * CC, flag);
  cvt_bf16<<<(CC * CC + 255) / 256, 256, 0, stream>>>(proj_w, 0, pw, CC * CC, flag);
  cvt_f32<<<(CC + 255) / 256, 256, 0, stream>>>(proj_b, pbf, CC, flag);

  // top-k path (fp32-exact, independent of the bf16 pipeline)
  qcls_kernel<<<dim3(BB, 12), 256, 0, stream>>>(x, qkv_w, qc, flag);
  gmat_kernel<<<dim3(BB, HH), 256, 0, stream>>>(qkv_w, qc, g, flag);
  score_kernel<<<(BB * NN + 3) / 4, 256, 0, stream>>>(x, g, wscore, flag);
  rank_kernel<<<BB, 256, 0, stream>>>(wscore, d_out, flag);

  const int nChunks = (BB + Bc - 1) / Bc;
  for (int cb = 0; cb < nChunks; cb++) {
    const int b0 = cb * Bc;
    const int bc = (BB - b0 < Bc) ? (BB - b0) : Bc;
    const int Mc = bc * NN;
    cvt_bf16<<<(Mc * CC + 255) / 256, 256, 0, stream>>>(
        x, (size_t)b0 * NN * CC, xb, Mc * CC, flag);
    qkv_gemm<<<dim3((Mc + 127) / 128, 18), 256, 0, stream>>>(xb, wb, qkvc, Mc, bc);
    attn_kernel<<<dim3(bc * HH, 4), 256, 0, stream>>>(qkvc, bc, Yc);
    proj_gemm<<<dim3((Mc + 127) / 128, 6), 256, 0, stream>>>(
        Yc, pw, pbf, d_out, (size_t)b0 * NN * CC, Mc, flag);
  }
}

// Round 7
// 520.500 us; speedup vs baseline: 5.0994x; 1.1069x over previous
//
#include <hip/hip_runtime.h>
#include <hip/hip_bf16.h>

// PoolingAttention: B=64 N=197 C=768 H=12 D=64. fp32 in/out (runtime-detected).
// out = [B*N*C] attention output ++ [B*160] keep_index.
//
// R7: attention restructured for residency: 1 block per (b,h) (grid 768 =
// 256 CUs x 3 blocks @ 54.3 KB LDS), V^T staged once, 4 q-strips per wave
// with no intra-loop barriers. cvt_x folded into qkv_gemm's A-stager
// (dual-dtype, row offset m0_g applied in-kernel per dtype).

#define BB 64
#define NN 197
#define CC 768
#define HH 12
#define DD 64
#define KEEP 160
#define SCALE_F 0.125f   // 64^-0.5
#define OUT0_ELEMS ((size_t)BB * NN * CC)   // 9,682,944
#define VST 212          // LDS row stride (u16): 8B-aligned rows, gcd(106,32)=2

typedef __attribute__((ext_vector_type(8))) short bf16x8_t;
typedef __attribute__((ext_vector_type(4))) float f32x4_t;

__device__ __forceinline__ float b2f(unsigned short u) {
  union { unsigned u; float f; } cv; cv.u = (unsigned)u << 16; return cv.f;
}
__device__ __forceinline__ unsigned short f2b(float f) {   // RNE, finite
  union { float f; unsigned u; } cv; cv.f = f;
  return (unsigned short)((cv.u + 0x7FFFu + ((cv.u >> 16) & 1u)) >> 16);
}
__device__ __forceinline__ float ldmix(const void* p, size_t i, int f32) {
  return f32 ? ((const float*)p)[i] : b2f(((const unsigned short*)p)[i]);
}
// 8 bf16 from LDS via two b64 reads (rows only 8B-aligned at VST=212)
__device__ __forceinline__ bf16x8_t ld8(const unsigned short* p) {
  short4 a = *(const short4*)p;
  short4 b = *(const short4*)(p + 4);
  bf16x8_t v = {a.x, a.y, a.z, a.w, b.x, b.y, b.z, b.w};
  return v;
}

// ---------------------------------------------------------------------------
__global__ void detect_kernel(const void* x, int* flag) {
  __shared__ int cnt;
  if (threadIdx.x == 0) cnt = 0;
  __syncthreads();
  const unsigned short* u = (const unsigned short*)x;
  int wild = 0;
  for (int i = threadIdx.x; i < 4096; i += 256) {
    int e = (u[i] >> 7) & 0xFF;
    wild += (e >= 140);
  }
  atomicAdd(&cnt, wild);
  __syncthreads();
  if (threadIdx.x == 0) *flag = (cnt > 100) ? 1 : 0;
}

__global__ void cvt_all(const void* qkv_w, const void* proj_w, const void* proj_b,
                        unsigned short* wb, unsigned short* pw, float* pbf,
                        const int* flag) {
  const int W3 = 3 * CC * CC, W1 = CC * CC;
  int i = blockIdx.x * 256 + threadIdx.x;
  const int f32 = *flag;
  if (i < W3) {
    wb[i] = f32 ? f2b(((const float*)qkv_w)[i]) : ((const unsigned short*)qkv_w)[i];
  } else if (i < W3 + W1) {
    int j = i - W3;
    pw[j] = f32 ? f2b(((const float*)proj_w)[j]) : ((const unsigned short*)proj_w)[j];
  } else if (i < W3 + W1 + CC) {
    int j = i - W3 - W1;
    pbf[j] = ldmix(proj_b, j, f32);
  }
}

// ---------------------------------------------------------------------------
// qkv_gemm: 128x128 LDS-staged MFMA GEMM; A read from RAW x (fp32 or bf16),
// rows offset by m_off (global row index = m_off + local row).
// ---------------------------------------------------------------------------
__global__ __launch_bounds__(256, 2) void qkv_gemm(
    const void* __restrict__ xraw, int m_off,
    const unsigned short* __restrict__ wb,
    unsigned short* __restrict__ qkvc, int Mc, int bc,
    const int* __restrict__ flag) {
  const int f32 = *flag;
  __shared__ unsigned short As[4096];
  __shared__ unsigned short Bs[4096];
  const int lane = threadIdx.x & 63;
  const int wave = threadIdx.x >> 6;
  const int l16  = lane & 15;
  const int quad = lane >> 4;
  const int wm = wave >> 1, wn = wave & 1;
  const int m0 = blockIdx.x * 128;
  const int n0 = blockIdx.y * 128;
  f32x4_t acc[4][4] = {};
  for (int kt = 0; kt < 24; kt++) {
    const int k0 = kt * 32;
    __syncthreads();
    #pragma unroll
    for (int ch = threadIdx.x; ch < 512; ch += 256) {
      int row = ch >> 2, kg = ch & 3;
      int gr = m0 + row; if (gr >= Mc) gr = Mc - 1;
      const size_t eoff = (size_t)(m_off + gr) * CC + k0 + kg * 8;
      bf16x8_t a;
      if (f32) {
        const float* xp = (const float*)xraw + eoff;
        float4 u0 = *(const float4*)xp;
        float4 u1 = *(const float4*)(xp + 4);
        a = bf16x8_t{(short)f2b(u0.x), (short)f2b(u0.y), (short)f2b(u0.z),
                     (short)f2b(u0.w), (short)f2b(u1.x), (short)f2b(u1.y),
                     (short)f2b(u1.z), (short)f2b(u1.w)};
      } else {
        a = *(const bf16x8_t*)((const unsigned short*)xraw + eoff);
      }
      *(bf16x8_t*)&As[(row >> 4) * 512 + (row & 15) * 32 + kg * 8] = a;
    }
    #pragma unroll
    for (int ch = threadIdx.x; ch < 512; ch += 256) {
      int row = ch >> 2, kg = ch & 3;
      *(bf16x8_t*)&Bs[(row >> 4) * 512 + (row & 15) * 32 + kg * 8] =
          *(const bf16x8_t*)(wb + (size_t)(n0 + row) * CC + k0 + kg * 8);
    }
    __syncthreads();
    bf16x8_t afr[4], bfr[4];
    #pragma unroll
    for (int r = 0; r < 4; r++)
      afr[r] = *(const bf16x8_t*)&As[(wm * 4 + r) * 512 + l16 * 32 + quad * 8];
    #pragma unroll
    for (int c = 0; c < 4; c++)
      bfr[c] = *(const bf16x8_t*)&Bs[(wn * 4 + c) * 512 + l16 * 32 + quad * 8];
    #pragma unroll
    for (int r = 0; r < 4; r++)
      #pragma unroll
      for (int c = 0; c < 4; c++)
        acc[r][c] = __builtin_amdgcn_mfma_f32_16x16x32_bf16(afr[r], bfr[c],
                                                            acc[r][c], 0, 0, 0);
  }
  #pragma unroll
  for (int c = 0; c < 4; c++) {
    const int col = n0 + wn * 64 + c * 16 + l16;
    const int s = col / CC;
    const int rem = col - s * CC;
    const int hc = rem >> 6, d = rem & 63;
    #pragma unroll
    for (int r = 0; r < 4; r++) {
      #pragma unroll
      for (int i = 0; i < 4; i++) {
        const int m = m0 + wm * 64 + r * 16 + quad * 4 + i;
        if (m < Mc) {
          const int bb = m / NN, n = m - bb * NN;
          qkvc[((((size_t)s * bc + bb) * HH + hc) * NN + n) * DD + d] =
              f2b(acc[r][c][i]);
        }
      }
    }
  }
}

// ---------------------------------------------------------------------------
// proj_gemm: 128x128 LDS-staged MFMA GEMM from bf16 ws, dual-dtype store.
// ---------------------------------------------------------------------------
__global__ __launch_bounds__(256, 2) void proj_gemm(
    const unsigned short* __restrict__ Yc,
    const unsigned short* __restrict__ pw,
    const float* __restrict__ pbf,
    void* __restrict__ out, size_t out_off, int Mc,
    const int* __restrict__ flag) {
  __shared__ unsigned short As[4096];
  __shared__ unsigned short Bs[4096];
  const int lane = threadIdx.x & 63;
  const int wave = threadIdx.x >> 6;
  const int l16  = lane & 15;
  const int quad = lane >> 4;
  const int wm = wave >> 1, wn = wave & 1;
  const int m0 = blockIdx.x * 128;
  const int n0 = blockIdx.y * 128;
  f32x4_t acc[4][4] = {};
  for (int kt = 0; kt < 24; kt++) {
    const int k0 = kt * 32;
    __syncthreads();
    #pragma unroll
    for (int ch = threadIdx.x; ch < 512; ch += 256) {
      int row = ch >> 2, kg = ch & 3;
      int gr = m0 + row; if (gr >= Mc) gr = Mc - 1;
      *(bf16x8_t*)&As[(row >> 4) * 512 + (row & 15) * 32 + kg * 8] =
          *(const bf16x8_t*)(Yc + (size_t)gr * CC + k0 + kg * 8);
    }
    #pragma unroll
    for (int ch = threadIdx.x; ch < 512; ch += 256) {
      int row = ch >> 2, kg = ch & 3;
      *(bf16x8_t*)&Bs[(row >> 4) * 512 + (row & 15) * 32 + kg * 8] =
          *(const bf16x8_t*)(pw + (size_t)(n0 + row) * CC + k0 + kg * 8);
    }
    __syncthreads();
    bf16x8_t afr[4], bfr[4];
    #pragma unroll
    for (int r = 0; r < 4; r++)
      afr[r] = *(const bf16x8_t*)&As[(wm * 4 + r) * 512 + l16 * 32 + quad * 8];
    #pragma unroll
    for (int c = 0; c < 4; c++)
      bfr[c] = *(const bf16x8_t*)&Bs[(wn * 4 + c) * 512 + l16 * 32 + quad * 8];
    #pragma unroll
    for (int r = 0; r < 4; r++)
      #pragma unroll
      for (int c = 0; c < 4; c++)
        acc[r][c] = __builtin_amdgcn_mfma_f32_16x16x32_bf16(afr[r], bfr[c],
                                                            acc[r][c], 0, 0, 0);
  }
  const int f32 = *flag;
  #pragma unroll
  for (int c = 0; c < 4; c++) {
    const int col = n0 + wn * 64 + c * 16 + l16;
    const float bv = pbf[col];
    #pragma unroll
    for (int r = 0; r < 4; r++) {
      #pragma unroll
      for (int i = 0; i < 4; i++) {
        const int m = m0 + wm * 64 + r * 16 + quad * 4 + i;
        if (m < Mc) {
          const float val = acc[r][c][i] + bv;
          const size_t oi = out_off + (size_t)m * CC + col;
          if (f32) ((float*)out)[oi] = val;
          else ((unsigned short*)out)[oi] = f2b(val);
        }
      }
    }
  }
}

// ---------------------------------------------------------------------------
// MFMA attention, residency-optimized. Grid (bc*HH); 4 waves/block; each wave
// loops q-strips si = it*4+wave (13 strips of 16 rows). LDS 54,272 B.
// ---------------------------------------------------------------------------
__global__ __launch_bounds__(256, 3) void attn_kernel(
    const unsigned short* __restrict__ qkvc, int bc,
    unsigned short* __restrict__ Yc) {
  const int bh = blockIdx.x;
  const int bb = bh / HH;
  const int h  = bh % HH;
  const size_t mat = (size_t)bc * HH * NN * DD;
  const unsigned short* q = qkvc + ((size_t)bb * HH + h) * NN * DD;
  const unsigned short* k = q + mat;
  const unsigned short* v = q + 2 * mat;

  __shared__ unsigned short Vt[DD * VST];     // 27,136 B (V^T, zero-padded)
  __shared__ unsigned short Pl[4][16 * VST];  // 27,136 B (per-wave P strip)

  const int lane = threadIdx.x & 63;
  const int wave = threadIdx.x >> 6;
  const int l16  = lane & 15;
  const int quad = lane >> 4;

  // stage V^T once: Vt[d=lane][key], keys 197..211 zeroed
  #pragma unroll
  for (int it = 0; it < 53; it++) {
    const int key = it * 4 + wave;
    unsigned short val = (key < NN) ? v[(size_t)key * DD + lane]
                                    : (unsigned short)0;
    Vt[lane * VST + key] = val;
  }
  __syncthreads();

  unsigned short* Pw = &Pl[wave][0];

  for (int it = 0; it < 4; it++) {
    const int si = it * 4 + wave;
    if (si >= 13) break;          // no barriers inside the loop: safe
    const int q0 = si * 16;

    int qrow = q0 + l16; if (qrow >= NN) qrow = NN - 1;
    const unsigned short* qp = q + (size_t)qrow * DD + quad * 8;
    const bf16x8_t aq0 = *(const bf16x8_t*)qp;
    const bf16x8_t aq1 = *(const bf16x8_t*)(qp + 32);

    // S strip: 16 q-rows x 208 keys, 26 MFMAs, K frags from global (L1/L2)
    f32x4_t sc[13];
    #pragma unroll
    for (int ct = 0; ct < 13; ct++) {
      int key = ct * 16 + l16; if (key >= NN) key = NN - 1;
      const unsigned short* kp = k + (size_t)key * DD + quad * 8;
      const bf16x8_t b0 = *(const bf16x8_t*)kp;
      const bf16x8_t b1 = *(const bf16x8_t*)(kp + 32);
      f32x4_t t = {0.f, 0.f, 0.f, 0.f};
      t = __builtin_amdgcn_mfma_f32_16x16x32_bf16(aq0, b0, t, 0, 0, 0);
      t = __builtin_amdgcn_mfma_f32_16x16x32_bf16(aq1, b1, t, 0, 0, 0);
      sc[ct] = t;
    }

    // softmax per row (row = quad*4+i), reduce across l16 via shfl
    float inv_l[4];
    #pragma unroll
    for (int i = 0; i < 4; i++) {
      float m = -1e30f;
      #pragma unroll
      for (int ct = 0; ct < 13; ct++)
        if (ct < 12 || l16 < 5) m = fmaxf(m, sc[ct][i] * SCALE_F);
      #pragma unroll
      for (int d = 1; d < 16; d <<= 1) m = fmaxf(m, __shfl_xor(m, d, 64));
      float s = 0.f;
      #pragma unroll
      for (int ct = 0; ct < 13; ct++) {
        const float p = (ct < 12 || l16 < 5) ? __expf(sc[ct][i] * SCALE_F - m)
                                             : 0.f;
        sc[ct][i] = p;
        s += p;
      }
      #pragma unroll
      for (int d = 1; d < 16; d <<= 1) s += __shfl_xor(s, d, 64);
      inv_l[i] = 1.0f / s;
    }

    // P -> per-wave LDS (A-layout, cols 0..207); same-wave ordering only
    #pragma unroll
    for (int i = 0; i < 4; i++) {
      const int ro = (quad * 4 + i) * VST;
      #pragma unroll
      for (int ct = 0; ct < 13; ct++)
        Pw[ro + ct * 16 + l16] = f2b(sc[ct][i]);
    }

    // O strip = P(16x208) @ V(208x64): 6 full 32-key chunks + 16-key tail
    f32x4_t oc[4] = {};
    #pragma unroll
    for (int ks = 0; ks < 6; ks++) {
      const bf16x8_t ap = ld8(&Pw[l16 * VST + ks * 32 + quad * 8]);
      #pragma unroll
      for (int dt = 0; dt < 4; dt++) {
        const bf16x8_t bv = ld8(&Vt[(dt * 16 + l16) * VST + ks * 32 + quad * 8]);
        oc[dt] = __builtin_amdgcn_mfma_f32_16x16x32_bf16(ap, bv, oc[dt], 0, 0, 0);
      }
    }
    {  // tail keys 192..207: quads 0,1 carry data, quads 2,3 zero frags
      const bf16x8_t zz = {};
      bf16x8_t ap = zz;
      if (quad < 2) ap = ld8(&Pw[l16 * VST + 192 + quad * 8]);
      #pragma unroll
      for (int dt = 0; dt < 4; dt++) {
        bf16x8_t bv = zz;
        if (quad < 2) bv = ld8(&Vt[(dt * 16 + l16) * VST + 192 + quad * 8]);
        oc[dt] = __builtin_amdgcn_mfma_f32_16x16x32_bf16(ap, bv, oc[dt], 0, 0, 0);
      }
    }

    #pragma unroll
    for (int i = 0; i < 4; i++) {
      const int n = q0 + quad * 4 + i;
      if (n < NN) {
        unsigned short* yp = Yc + ((size_t)bb * NN + n) * CC + h * DD;
        #pragma unroll
        for (int dt = 0; dt < 4; dt++)
          yp[dt * 16 + l16] = f2b(oc[dt][i] * inv_l[i]);
      }
    }
  }
}

// ---------------------------------------------------------------------------
// Top-k path, fp32-exact (matches np reference ranking).
// ---------------------------------------------------------------------------
__global__ __launch_bounds__(256, 4) void qcls_kernel(
    const void* __restrict__ x, const void* __restrict__ qkv_w,
    float* __restrict__ qc, const int* __restrict__ flag) {
  const int b = blockIdx.x;
  const int f32 = *flag;
  __shared__ float x0[CC];
  __shared__ float red[4][64];
  const size_t xb0 = (size_t)b * NN * CC;
  for (int i = threadIdx.x; i < CC; i += 256) x0[i] = ldmix(x, xb0 + i, f32);
  __syncthreads();

  const int il = threadIdx.x & 63;
  const int part = threadIdx.x >> 6;
  const int i = blockIdx.y * 64 + il;
  const size_t ro = (size_t)i * CC + part * 192;
  float s = 0.f;
  #pragma unroll 8
  for (int c = 0; c < 192; c++) s += x0[part * 192 + c] * ldmix(qkv_w, ro + c, f32);
  red[part][il] = s;
  __syncthreads();
  if (part == 0)
    qc[(size_t)b * CC + i] = red[0][il] + red[1][il] + red[2][il] + red[3][il];
}

__global__ __launch_bounds__(256, 4) void gmat_kernel(
    const void* __restrict__ qkv_w, const float* __restrict__ qc,
    float* __restrict__ g, const int* __restrict__ flag) {
  const int b = blockIdx.x, h = blockIdx.y;
  const int f32 = *flag;
  __shared__ float qh[DD];
  if (threadIdx.x < DD) qh[threadIdx.x] = qc[(size_t)b * CC + h * DD + threadIdx.x];
  __syncthreads();
  const int c0 = threadIdx.x, c1 = c0 + 256, c2 = c1 + 256;
  float a0 = 0.f, a1 = 0.f, a2 = 0.f;
  for (int d = 0; d < DD; d++) {
    const size_t ro = (size_t)(CC + h * DD + d) * CC;
    const float qv = qh[d];
    a0 += ldmix(qkv_w, ro + c0, f32) * qv;
    a1 += ldmix(qkv_w, ro + c1, f32) * qv;
    a2 += ldmix(qkv_w, ro + c2, f32) * qv;
  }
  float* gb = g + ((size_t)b * HH + h) * CC;
  gb[c0] = a0; gb[c1] = a1; gb[c2] = a2;
}

__global__ __launch_bounds__(256, 4) void score_kernel(
    const void* __restrict__ x, const float* __restrict__ g,
    float* __restrict__ wscore, const int* __restrict__ flag) {
  const int idx = blockIdx.x * 4 + (threadIdx.x >> 6);
  if (idx >= BB * NN) return;
  const int b = idx / NN, n = idx - b * NN;
  const int lane = threadIdx.x & 63;
  const int f32 = *flag;
  const size_t xr = ((size_t)b * NN + n) * CC;
  float xv[12];
  #pragma unroll
  for (int j = 0; j < 12; j++) xv[j] = ldmix(x, xr + j * 64 + lane, f32);
  const float* gb = g + (size_t)b * HH * CC;
  float acc = 0.f;
  #pragma unroll
  for (int h = 0; h < HH; h++) {
    const float* gh = gb + (size_t)h * CC;
    float p = 0.f;
    #pragma unroll
    for (int j = 0; j < 12; j++) p += xv[j] * gh[j * 64 + lane];
    #pragma unroll
    for (int m = 32; m; m >>= 1) p += __shfl_xor(p, m, 64);
    acc += fabsf(p);
  }
  if (lane == 0) wscore[(size_t)b * NN + n] = acc;
}

__global__ __launch_bounds__(256, 4) void rank_kernel(
    const float* __restrict__ wscore, void* __restrict__ out,
    const int* __restrict__ flag) {
  const int b = blockIdx.x;
  const int f32 = *flag;
  __shared__ float wgt[NN];
  __shared__ int   rank[NN];
  if (threadIdx.x < NN) wgt[threadIdx.x] = wscore[(size_t)b * NN + threadIdx.x];
  __syncthreads();
  const int n = threadIdx.x;
  if (n < NN) {
    float wi = wgt[n];
    int rk = 0;
    for (int j = 0; j < NN; j++) {
      float wj = wgt[j];
      rk += (wj > wi) || (wj == wi && j < n);   // stable top_k tie-break
    }
    rank[n] = rk;
  }
  __syncthreads();
  if (n < NN && rank[n] < KEEP) {
    int pos = 0;
    for (int j = 0; j < n; j++) pos += (rank[j] < KEEP);
    const size_t oi = OUT0_ELEMS + (size_t)b * KEEP + pos;
    if (f32) ((float*)out)[oi] = (float)n;
    else ((unsigned short*)out)[oi] = f2b((float)n);
  }
}

// ---------------------------------------------------------------------------
extern "C" void kernel_launch(void* const* d_in, const int* in_sizes, int n_in,
                              void* d_out, int out_size, void* d_ws, size_t ws_size,
                              hipStream_t stream) {
  const void* x      = d_in[0];
  const void* qkv_w  = d_in[1];
  const void* proj_w = d_in[2];
  const void* proj_b = d_in[3];

  char* wsb = (char*)d_ws;
  int* flag = (int*)wsb;
  unsigned short* wb  = (unsigned short*)(wsb + 256);
  unsigned short* pw  = (unsigned short*)(wsb + 256 + 3538944);
  float* pbf    = (float*)(wsb + 256 + 3538944 + 1179648);
  float* qc     = (float*)(wsb + 256 + 3538944 + 1179648 + 4096);
  float* g      = qc + (size_t)BB * CC;
  float* wscore = g + (size_t)BB * HH * CC;
  const size_t fixed = 256 + 3538944 + 1179648 + 4096 + 196608 + 2359296 + 51200;
  char* chunk = wsb + fixed;

  const size_t per_batch = 3ull * HH * NN * DD * 2   // qkvc
                         + (size_t)NN * CC * 2;      // Yc  = 1,210,368
  int Bc = BB;
  while (Bc > 1 && fixed + (size_t)Bc * per_batch > ws_size) Bc >>= 1;

  unsigned short* qkvc = (unsigned short*)chunk;
  unsigned short* Yc   = qkvc + 3ull * Bc * HH * NN * DD;

  detect_kernel<<<1, 256, 0, stream>>>(x, flag);
  const int cvt_n = 3 * CC * CC + CC * CC + CC;
  cvt_all<<<(cvt_n + 255) / 256, 256, 0, stream>>>(qkv_w, proj_w, proj_b,
                                                   wb, pw, pbf, flag);

  // top-k path (fp32-exact, independent of the bf16 pipeline)
  qcls_kernel<<<dim3(BB, 12), 256, 0, stream>>>(x, qkv_w, qc, flag);
  gmat_kernel<<<dim3(BB, HH), 256, 0, stream>>>(qkv_w, qc, g, flag);
  score_kernel<<<(BB * NN + 3) / 4, 256, 0, stream>>>(x, g, wscore, flag);
  rank_kernel<<<BB, 256, 0, stream>>>(wscore, d_out, flag);

  const int nChunks = (BB + Bc - 1) / Bc;
  for (int cb = 0; cb < nChunks; cb++) {
    const int b0 = cb * Bc;
    const int bc = (BB - b0 < Bc) ? (BB - b0) : Bc;
    const int Mc = bc * NN;
    qkv_gemm<<<dim3((Mc + 127) / 128, 18), 256, 0, stream>>>(
        x, b0 * NN, wb, qkvc, Mc, bc, flag);
    attn_kernel<<<dim3(bc * HH), 256, 0, stream>>>(qkvc, bc, Yc);
    proj_gemm<<<dim3((Mc + 127) / 128, 6), 256, 0, stream>>>(
        Yc, pw, pbf, d_out, (size_t)b0 * NN * CC, Mc, flag);
  }
}

// Round 8
// 479.916 us; speedup vs baseline: 5.5306x; 1.0846x over previous
//
#include <hip/hip_runtime.h>
#include <hip/hip_bf16.h>

// PoolingAttention: B=64 N=197 C=768 H=12 D=64. fp32 in/out (runtime-detected).
// out = [B*N*C] attention output ++ [B*160] keep_index.
//
// R8: XCD-aware block swizzle for both GEMMs. R7's grid (99,18) streamed the
// 38.7 MB fp32 x once per col-tile; per-XCD L2s re-fetched it 8x (FETCH=311MB,
// MfmaUtil 12%). Now all col-tiles of a row-tile run consecutively on ONE XCD
// (bid%8 = XCD round-robin), so the A-tile is HBM-fetched once and L2-served.

#define BB 64
#define NN 197
#define CC 768
#define HH 12
#define DD 64
#define KEEP 160
#define SCALE_F 0.125f   // 64^-0.5
#define OUT0_ELEMS ((size_t)BB * NN * CC)   // 9,682,944
#define VST 212          // LDS row stride (u16): 8B-aligned rows, gcd(106,32)=2

typedef __attribute__((ext_vector_type(8))) short bf16x8_t;
typedef __attribute__((ext_vector_type(4))) float f32x4_t;

__device__ __forceinline__ float b2f(unsigned short u) {
  union { unsigned u; float f; } cv; cv.u = (unsigned)u << 16; return cv.f;
}
__device__ __forceinline__ unsigned short f2b(float f) {   // RNE, finite
  union { float f; unsigned u; } cv; cv.f = f;
  return (unsigned short)((cv.u + 0x7FFFu + ((cv.u >> 16) & 1u)) >> 16);
}
__device__ __forceinline__ float ldmix(const void* p, size_t i, int f32) {
  return f32 ? ((const float*)p)[i] : b2f(((const unsigned short*)p)[i]);
}
// 8 bf16 from LDS via two b64 reads (rows only 8B-aligned at VST=212)
__device__ __forceinline__ bf16x8_t ld8(const unsigned short* p) {
  short4 a = *(const short4*)p;
  short4 b = *(const short4*)(p + 4);
  bf16x8_t v = {a.x, a.y, a.z, a.w, b.x, b.y, b.z, b.w};
  return v;
}

// ---------------------------------------------------------------------------
__global__ void detect_kernel(const void* x, int* flag) {
  __shared__ int cnt;
  if (threadIdx.x == 0) cnt = 0;
  __syncthreads();
  const unsigned short* u = (const unsigned short*)x;
  int wild = 0;
  for (int i = threadIdx.x; i < 4096; i += 256) {
    int e = (u[i] >> 7) & 0xFF;
    wild += (e >= 140);
  }
  atomicAdd(&cnt, wild);
  __syncthreads();
  if (threadIdx.x == 0) *flag = (cnt > 100) ? 1 : 0;
}

__global__ void cvt_all(const void* qkv_w, const void* proj_w, const void* proj_b,
                        unsigned short* wb, unsigned short* pw, float* pbf,
                        const int* flag) {
  const int W3 = 3 * CC * CC, W1 = CC * CC;
  int i = blockIdx.x * 256 + threadIdx.x;
  const int f32 = *flag;
  if (i < W3) {
    wb[i] = f32 ? f2b(((const float*)qkv_w)[i]) : ((const unsigned short*)qkv_w)[i];
  } else if (i < W3 + W1) {
    int j = i - W3;
    pw[j] = f32 ? f2b(((const float*)proj_w)[j]) : ((const unsigned short*)proj_w)[j];
  } else if (i < W3 + W1 + CC) {
    int j = i - W3 - W1;
    pbf[j] = ldmix(proj_b, j, f32);
  }
}

// ---------------------------------------------------------------------------
// qkv_gemm: 128x128 LDS-staged MFMA GEMM; A read from RAW x (fp32 or bf16).
// 1-D grid, XCD-swizzled: all 18 col-tiles of a row-tile on one XCD.
// ---------------------------------------------------------------------------
__global__ __launch_bounds__(256, 2) void qkv_gemm(
    const void* __restrict__ xraw, int m_off,
    const unsigned short* __restrict__ wb,
    unsigned short* __restrict__ qkvc, int Mc, int bc, int nRow,
    const int* __restrict__ flag) {
  const int xcd = blockIdx.x & 7;
  const int seq = blockIdx.x >> 3;
  const int colt = seq % 18;
  const int rowt = (seq / 18) * 8 + xcd;
  if (rowt >= nRow) return;
  const int m0 = rowt * 128;
  const int n0 = colt * 128;

  const int f32 = *flag;
  __shared__ unsigned short As[4096];
  __shared__ unsigned short Bs[4096];
  const int lane = threadIdx.x & 63;
  const int wave = threadIdx.x >> 6;
  const int l16  = lane & 15;
  const int quad = lane >> 4;
  const int wm = wave >> 1, wn = wave & 1;
  f32x4_t acc[4][4] = {};
  for (int kt = 0; kt < 24; kt++) {
    const int k0 = kt * 32;
    __syncthreads();
    #pragma unroll
    for (int ch = threadIdx.x; ch < 512; ch += 256) {
      int row = ch >> 2, kg = ch & 3;
      int gr = m0 + row; if (gr >= Mc) gr = Mc - 1;
      const size_t eoff = (size_t)(m_off + gr) * CC + k0 + kg * 8;
      bf16x8_t a;
      if (f32) {
        const float* xp = (const float*)xraw + eoff;
        float4 u0 = *(const float4*)xp;
        float4 u1 = *(const float4*)(xp + 4);
        a = bf16x8_t{(short)f2b(u0.x), (short)f2b(u0.y), (short)f2b(u0.z),
                     (short)f2b(u0.w), (short)f2b(u1.x), (short)f2b(u1.y),
                     (short)f2b(u1.z), (short)f2b(u1.w)};
      } else {
        a = *(const bf16x8_t*)((const unsigned short*)xraw + eoff);
      }
      *(bf16x8_t*)&As[(row >> 4) * 512 + (row & 15) * 32 + kg * 8] = a;
    }
    #pragma unroll
    for (int ch = threadIdx.x; ch < 512; ch += 256) {
      int row = ch >> 2, kg = ch & 3;
      *(bf16x8_t*)&Bs[(row >> 4) * 512 + (row & 15) * 32 + kg * 8] =
          *(const bf16x8_t*)(wb + (size_t)(n0 + row) * CC + k0 + kg * 8);
    }
    __syncthreads();
    bf16x8_t afr[4], bfr[4];
    #pragma unroll
    for (int r = 0; r < 4; r++)
      afr[r] = *(const bf16x8_t*)&As[(wm * 4 + r) * 512 + l16 * 32 + quad * 8];
    #pragma unroll
    for (int c = 0; c < 4; c++)
      bfr[c] = *(const bf16x8_t*)&Bs[(wn * 4 + c) * 512 + l16 * 32 + quad * 8];
    #pragma unroll
    for (int r = 0; r < 4; r++)
      #pragma unroll
      for (int c = 0; c < 4; c++)
        acc[r][c] = __builtin_amdgcn_mfma_f32_16x16x32_bf16(afr[r], bfr[c],
                                                            acc[r][c], 0, 0, 0);
  }
  #pragma unroll
  for (int c = 0; c < 4; c++) {
    const int col = n0 + wn * 64 + c * 16 + l16;
    const int s = col / CC;
    const int rem = col - s * CC;
    const int hc = rem >> 6, d = rem & 63;
    #pragma unroll
    for (int r = 0; r < 4; r++) {
      #pragma unroll
      for (int i = 0; i < 4; i++) {
        const int m = m0 + wm * 64 + r * 16 + quad * 4 + i;
        if (m < Mc) {
          const int bb = m / NN, n = m - bb * NN;
          qkvc[((((size_t)s * bc + bb) * HH + hc) * NN + n) * DD + d] =
              f2b(acc[r][c][i]);
        }
      }
    }
  }
}

// ---------------------------------------------------------------------------
// proj_gemm: 128x128 LDS-staged MFMA GEMM from bf16 ws, dual-dtype store.
// XCD-swizzled like qkv_gemm (6 col-tiles).
// ---------------------------------------------------------------------------
__global__ __launch_bounds__(256, 2) void proj_gemm(
    const unsigned short* __restrict__ Yc,
    const unsigned short* __restrict__ pw,
    const float* __restrict__ pbf,
    void* __restrict__ out, size_t out_off, int Mc, int nRow,
    const int* __restrict__ flag) {
  const int xcd = blockIdx.x & 7;
  const int seq = blockIdx.x >> 3;
  const int colt = seq % 6;
  const int rowt = (seq / 6) * 8 + xcd;
  if (rowt >= nRow) return;
  const int m0 = rowt * 128;
  const int n0 = colt * 128;

  __shared__ unsigned short As[4096];
  __shared__ unsigned short Bs[4096];
  const int lane = threadIdx.x & 63;
  const int wave = threadIdx.x >> 6;
  const int l16  = lane & 15;
  const int quad = lane >> 4;
  const int wm = wave >> 1, wn = wave & 1;
  f32x4_t acc[4][4] = {};
  for (int kt = 0; kt < 24; kt++) {
    const int k0 = kt * 32;
    __syncthreads();
    #pragma unroll
    for (int ch = threadIdx.x; ch < 512; ch += 256) {
      int row = ch >> 2, kg = ch & 3;
      int gr = m0 + row; if (gr >= Mc) gr = Mc - 1;
      *(bf16x8_t*)&As[(row >> 4) * 512 + (row & 15) * 32 + kg * 8] =
          *(const bf16x8_t*)(Yc + (size_t)gr * CC + k0 + kg * 8);
    }
    #pragma unroll
    for (int ch = threadIdx.x; ch < 512; ch += 256) {
      int row = ch >> 2, kg = ch & 3;
      *(bf16x8_t*)&Bs[(row >> 4) * 512 + (row & 15) * 32 + kg * 8] =
          *(const bf16x8_t*)(pw + (size_t)(n0 + row) * CC + k0 + kg * 8);
    }
    __syncthreads();
    bf16x8_t afr[4], bfr[4];
    #pragma unroll
    for (int r = 0; r < 4; r++)
      afr[r] = *(const bf16x8_t*)&As[(wm * 4 + r) * 512 + l16 * 32 + quad * 8];
    #pragma unroll
    for (int c = 0; c < 4; c++)
      bfr[c] = *(const bf16x8_t*)&Bs[(wn * 4 + c) * 512 + l16 * 32 + quad * 8];
    #pragma unroll
    for (int r = 0; r < 4; r++)
      #pragma unroll
      for (int c = 0; c < 4; c++)
        acc[r][c] = __builtin_amdgcn_mfma_f32_16x16x32_bf16(afr[r], bfr[c],
                                                            acc[r][c], 0, 0, 0);
  }
  const int f32 = *flag;
  #pragma unroll
  for (int c = 0; c < 4; c++) {
    const int col = n0 + wn * 64 + c * 16 + l16;
    const float bv = pbf[col];
    #pragma unroll
    for (int r = 0; r < 4; r++) {
      #pragma unroll
      for (int i = 0; i < 4; i++) {
        const int m = m0 + wm * 64 + r * 16 + quad * 4 + i;
        if (m < Mc) {
          const float val = acc[r][c][i] + bv;
          const size_t oi = out_off + (size_t)m * CC + col;
          if (f32) ((float*)out)[oi] = val;
          else ((unsigned short*)out)[oi] = f2b(val);
        }
      }
    }
  }
}

// ---------------------------------------------------------------------------
// MFMA attention (R7 structure). Grid (bc*HH); 4 waves/block; each wave loops
// q-strips si = it*4+wave (13 strips of 16 rows). LDS 54,272 B.
// ---------------------------------------------------------------------------
__global__ __launch_bounds__(256, 3) void attn_kernel(
    const unsigned short* __restrict__ qkvc, int bc,
    unsigned short* __restrict__ Yc) {
  const int bh = blockIdx.x;
  const int bb = bh / HH;
  const int h  = bh % HH;
  const size_t mat = (size_t)bc * HH * NN * DD;
  const unsigned short* q = qkvc + ((size_t)bb * HH + h) * NN * DD;
  const unsigned short* k = q + mat;
  const unsigned short* v = q + 2 * mat;

  __shared__ unsigned short Vt[DD * VST];     // 27,136 B (V^T, zero-padded)
  __shared__ unsigned short Pl[4][16 * VST];  // 27,136 B (per-wave P strip)

  const int lane = threadIdx.x & 63;
  const int wave = threadIdx.x >> 6;
  const int l16  = lane & 15;
  const int quad = lane >> 4;

  // stage V^T once: Vt[d=lane][key], keys 197..211 zeroed
  #pragma unroll
  for (int it = 0; it < 53; it++) {
    const int key = it * 4 + wave;
    unsigned short val = (key < NN) ? v[(size_t)key * DD + lane]
                                    : (unsigned short)0;
    Vt[lane * VST + key] = val;
  }
  __syncthreads();

  unsigned short* Pw = &Pl[wave][0];

  for (int it = 0; it < 4; it++) {
    const int si = it * 4 + wave;
    if (si >= 13) break;          // no barriers inside the loop: safe
    const int q0 = si * 16;

    int qrow = q0 + l16; if (qrow >= NN) qrow = NN - 1;
    const unsigned short* qp = q + (size_t)qrow * DD + quad * 8;
    const bf16x8_t aq0 = *(const bf16x8_t*)qp;
    const bf16x8_t aq1 = *(const bf16x8_t*)(qp + 32);

    // S strip: 16 q-rows x 208 keys, 26 MFMAs, K frags from global (L1/L2)
    f32x4_t sc[13];
    #pragma unroll
    for (int ct = 0; ct < 13; ct++) {
      int key = ct * 16 + l16; if (key >= NN) key = NN - 1;
      const unsigned short* kp = k + (size_t)key * DD + quad * 8;
      const bf16x8_t b0 = *(const bf16x8_t*)kp;
      const bf16x8_t b1 = *(const bf16x8_t*)(kp + 32);
      f32x4_t t = {0.f, 0.f, 0.f, 0.f};
      t = __builtin_amdgcn_mfma_f32_16x16x32_bf16(aq0, b0, t, 0, 0, 0);
      t = __builtin_amdgcn_mfma_f32_16x16x32_bf16(aq1, b1, t, 0, 0, 0);
      sc[ct] = t;
    }

    // softmax per row (row = quad*4+i), reduce across l16 via shfl
    float inv_l[4];
    #pragma unroll
    for (int i = 0; i < 4; i++) {
      float m = -1e30f;
      #pragma unroll
      for (int ct = 0; ct < 13; ct++)
        if (ct < 12 || l16 < 5) m = fmaxf(m, sc[ct][i] * SCALE_F);
      #pragma unroll
      for (int d = 1; d < 16; d <<= 1) m = fmaxf(m, __shfl_xor(m, d, 64));
      float s = 0.f;
      #pragma unroll
      for (int ct = 0; ct < 13; ct++) {
        const float p = (ct < 12 || l16 < 5) ? __expf(sc[ct][i] * SCALE_F - m)
                                             : 0.f;
        sc[ct][i] = p;
        s += p;
      }
      #pragma unroll
      for (int d = 1; d < 16; d <<= 1) s += __shfl_xor(s, d, 64);
      inv_l[i] = 1.0f / s;
    }

    // P -> per-wave LDS (A-layout, cols 0..207); same-wave ordering only
    #pragma unroll
    for (int i = 0; i < 4; i++) {
      const int ro = (quad * 4 + i) * VST;
      #pragma unroll
      for (int ct = 0; ct < 13; ct++)
        Pw[ro + ct * 16 + l16] = f2b(sc[ct][i]);
    }

    // O strip = P(16x208) @ V(208x64): 6 full 32-key chunks + 16-key tail
    f32x4_t oc[4] = {};
    #pragma unroll
    for (int ks = 0; ks < 6; ks++) {
      const bf16x8_t ap = ld8(&Pw[l16 * VST + ks * 32 + quad * 8]);
      #pragma unroll
      for (int dt = 0; dt < 4; dt++) {
        const bf16x8_t bv = ld8(&Vt[(dt * 16 + l16) * VST + ks * 32 + quad * 8]);
        oc[dt] = __builtin_amdgcn_mfma_f32_16x16x32_bf16(ap, bv, oc[dt], 0, 0, 0);
      }
    }
    {  // tail keys 192..207: quads 0,1 carry data, quads 2,3 zero frags
      const bf16x8_t zz = {};
      bf16x8_t ap = zz;
      if (quad < 2) ap = ld8(&Pw[l16 * VST + 192 + quad * 8]);
      #pragma unroll
      for (int dt = 0; dt < 4; dt++) {
        bf16x8_t bv = zz;
        if (quad < 2) bv = ld8(&Vt[(dt * 16 + l16) * VST + 192 + quad * 8]);
        oc[dt] = __builtin_amdgcn_mfma_f32_16x16x32_bf16(ap, bv, oc[dt], 0, 0, 0);
      }
    }

    #pragma unroll
    for (int i = 0; i < 4; i++) {
      const int n = q0 + quad * 4 + i;
      if (n < NN) {
        unsigned short* yp = Yc + ((size_t)bb * NN + n) * CC + h * DD;
        #pragma unroll
        for (int dt = 0; dt < 4; dt++)
          yp[dt * 16 + l16] = f2b(oc[dt][i] * inv_l[i]);
      }
    }
  }
}

// ---------------------------------------------------------------------------
// Top-k path, fp32-exact (matches np reference ranking).
// ---------------------------------------------------------------------------
__global__ __launch_bounds__(256, 4) void qcls_kernel(
    const void* __restrict__ x, const void* __restrict__ qkv_w,
    float* __restrict__ qc, const int* __restrict__ flag) {
  const int b = blockIdx.x;
  const int f32 = *flag;
  __shared__ float x0[CC];
  __shared__ float red[4][64];
  const size_t xb0 = (size_t)b * NN * CC;
  for (int i = threadIdx.x; i < CC; i += 256) x0[i] = ldmix(x, xb0 + i, f32);
  __syncthreads();

  const int il = threadIdx.x & 63;
  const int part = threadIdx.x >> 6;
  const int i = blockIdx.y * 64 + il;
  const size_t ro = (size_t)i * CC + part * 192;
  float s = 0.f;
  #pragma unroll 8
  for (int c = 0; c < 192; c++) s += x0[part * 192 + c] * ldmix(qkv_w, ro + c, f32);
  red[part][il] = s;
  __syncthreads();
  if (part == 0)
    qc[(size_t)b * CC + i] = red[0][il] + red[1][il] + red[2][il] + red[3][il];
}

__global__ __launch_bounds__(256, 4) void gmat_kernel(
    const void* __restrict__ qkv_w, const float* __restrict__ qc,
    float* __restrict__ g, const int* __restrict__ flag) {
  const int b = blockIdx.x, h = blockIdx.y;
  const int f32 = *flag;
  __shared__ float qh[DD];
  if (threadIdx.x < DD) qh[threadIdx.x] = qc[(size_t)b * CC + h * DD + threadIdx.x];
  __syncthreads();
  const int c0 = threadIdx.x, c1 = c0 + 256, c2 = c1 + 256;
  float a0 = 0.f, a1 = 0.f, a2 = 0.f;
  for (int d = 0; d < DD; d++) {
    const size_t ro = (size_t)(CC + h * DD + d) * CC;
    const float qv = qh[d];
    a0 += ldmix(qkv_w, ro + c0, f32) * qv;
    a1 += ldmix(qkv_w, ro + c1, f32) * qv;
    a2 += ldmix(qkv_w, ro + c2, f32) * qv;
  }
  float* gb = g + ((size_t)b * HH + h) * CC;
  gb[c0] = a0; gb[c1] = a1; gb[c2] = a2;
}

__global__ __launch_bounds__(256, 4) void score_kernel(
    const void* __restrict__ x, const float* __restrict__ g,
    float* __restrict__ wscore, const int* __restrict__ flag) {
  const int idx = blockIdx.x * 4 + (threadIdx.x >> 6);
  if (idx >= BB * NN) return;
  const int b = idx / NN, n = idx - b * NN;
  const int lane = threadIdx.x & 63;
  const int f32 = *flag;
  const size_t xr = ((size_t)b * NN + n) * CC;
  float xv[12];
  #pragma unroll
  for (int j = 0; j < 12; j++) xv[j] = ldmix(x, xr + j * 64 + lane, f32);
  const float* gb = g + (size_t)b * HH * CC;
  float acc = 0.f;
  #pragma unroll
  for (int h = 0; h < HH; h++) {
    const float* gh = gb + (size_t)h * CC;
    float p = 0.f;
    #pragma unroll
    for (int j = 0; j < 12; j++) p += xv[j] * gh[j * 64 + lane];
    #pragma unroll
    for (int m = 32; m; m >>= 1) p += __shfl_xor(p, m, 64);
    acc += fabsf(p);
  }
  if (lane == 0) wscore[(size_t)b * NN + n] = acc;
}

__global__ __launch_bounds__(256, 4) void rank_kernel(
    const float* __restrict__ wscore, void* __restrict__ out,
    const int* __restrict__ flag) {
  const int b = blockIdx.x;
  const int f32 = *flag;
  __shared__ float wgt[NN];
  __shared__ int   rank[NN];
  if (threadIdx.x < NN) wgt[threadIdx.x] = wscore[(size_t)b * NN + threadIdx.x];
  __syncthreads();
  const int n = threadIdx.x;
  if (n < NN) {
    float wi = wgt[n];
    int rk = 0;
    for (int j = 0; j < NN; j++) {
      float wj = wgt[j];
      rk += (wj > wi) || (wj == wi && j < n);   // stable top_k tie-break
    }
    rank[n] = rk;
  }
  __syncthreads();
  if (n < NN && rank[n] < KEEP) {
    int pos = 0;
    for (int j = 0; j < n; j++) pos += (rank[j] < KEEP);
    const size_t oi = OUT0_ELEMS + (size_t)b * KEEP + pos;
    if (f32) ((float*)out)[oi] = (float)n;
    else ((unsigned short*)out)[oi] = f2b((float)n);
  }
}

// ---------------------------------------------------------------------------
extern "C" void kernel_launch(void* const* d_in, const int* in_sizes, int n_in,
                              void* d_out, int out_size, void* d_ws, size_t ws_size,
                              hipStream_t stream) {
  const void* x      = d_in[0];
  const void* qkv_w  = d_in[1];
  const void* proj_w = d_in[2];
  const void* proj_b = d_in[3];

  char* wsb = (char*)d_ws;
  int* flag = (int*)wsb;
  unsigned short* wb  = (unsigned short*)(wsb + 256);
  unsigned short* pw  = (unsigned short*)(wsb + 256 + 3538944);
  float* pbf    = (float*)(wsb + 256 + 3538944 + 1179648);
  float* qc     = (float*)(wsb + 256 + 3538944 + 1179648 + 4096);
  float* g      = qc + (size_t)BB * CC;
  float* wscore = g + (size_t)BB * HH * CC;
  const size_t fixed = 256 + 3538944 + 1179648 + 4096 + 196608 + 2359296 + 51200;
  char* chunk = wsb + fixed;

  const size_t per_batch = 3ull * HH * NN * DD * 2   // qkvc
                         + (size_t)NN * CC * 2;      // Yc  = 1,210,368
  int Bc = BB;
  while (Bc > 1 && fixed + (size_t)Bc * per_batch > ws_size) Bc >>= 1;

  unsigned short* qkvc = (unsigned short*)chunk;
  unsigned short* Yc   = qkvc + 3ull * Bc * HH * NN * DD;

  detect_kernel<<<1, 256, 0, stream>>>(x, flag);
  const int cvt_n = 3 * CC * CC + CC * CC + CC;
  cvt_all<<<(cvt_n + 255) / 256, 256, 0, stream>>>(qkv_w, proj_w, proj_b,
                                                   wb, pw, pbf, flag);

  // top-k path (fp32-exact, independent of the bf16 pipeline)
  qcls_kernel<<<dim3(BB, 12), 256, 0, stream>>>(x, qkv_w, qc, flag);
  gmat_kernel<<<dim3(BB, HH), 256, 0, stream>>>(qkv_w, qc, g, flag);
  score_kernel<<<(BB * NN + 3) / 4, 256, 0, stream>>>(x, g, wscore, flag);
  rank_kernel<<<BB, 256, 0, stream>>>(wscore, d_out, flag);

  const int nChunks = (BB + Bc - 1) / Bc;
  for (int cb = 0; cb < nChunks; cb++) {
    const int b0 = cb * Bc;
    const int bc = (BB - b0 < Bc) ? (BB - b0) : Bc;
    const int Mc = bc * NN;
    const int nRowQ = (Mc + 127) / 128;
    const int gridQ = 8 * 18 * ((nRowQ + 7) / 8);
    qkv_gemm<<<gridQ, 256, 0, stream>>>(
        x, b0 * NN, wb, qkvc, Mc, bc, nRowQ, flag);
    attn_kernel<<<dim3(bc * HH), 256, 0, stream>>>(qkvc, bc, Yc);
    const int gridP = 8 * 6 * ((nRowQ + 7) / 8);
    proj_gemm<<<gridP, 256, 0, stream>>>(
        Yc, pw, pbf, d_out, (size_t)b0 * NN * CC, Mc, nRowQ, flag);
  }
}

// Round 9
// 395.045 us; speedup vs baseline: 6.7188x; 1.2148x over previous
//
#include <hip/hip_runtime.h>
#include <hip/hip_bf16.h>

// PoolingAttention: B=64 N=197 C=768 H=12 D=64. fp32 in/out (runtime-detected).
// out = [B*N*C] attention output ++ [B*160] keep_index.
//
// R9: (1) x pre-converted to bf16 once (cvt_x) instead of 18x in qkv_gemm's
// A-stager (R8: VALUBusy 29% from redundant f32->bf16); (2) GEMMs at
// launch_bounds(256,4) for 4 blocks/CU barrier overlap; (3) qcls_kernel
// rewritten coalesced (one wave per output, lanes along K).

#define BB 64
#define NN 197
#define CC 768
#define HH 12
#define DD 64
#define KEEP 160
#define SCALE_F 0.125f   // 64^-0.5
#define OUT0_ELEMS ((size_t)BB * NN * CC)   // 9,682,944
#define VST 212          // LDS row stride (u16): 8B-aligned rows, gcd(106,32)=2

typedef __attribute__((ext_vector_type(8))) short bf16x8_t;
typedef __attribute__((ext_vector_type(4))) float f32x4_t;

__device__ __forceinline__ float b2f(unsigned short u) {
  union { unsigned u; float f; } cv; cv.u = (unsigned)u << 16; return cv.f;
}
__device__ __forceinline__ unsigned short f2b(float f) {   // RNE, finite
  union { float f; unsigned u; } cv; cv.f = f;
  return (unsigned short)((cv.u + 0x7FFFu + ((cv.u >> 16) & 1u)) >> 16);
}
__device__ __forceinline__ float ldmix(const void* p, size_t i, int f32) {
  return f32 ? ((const float*)p)[i] : b2f(((const unsigned short*)p)[i]);
}
// 8 bf16 from LDS via two b64 reads (rows only 8B-aligned at VST=212)
__device__ __forceinline__ bf16x8_t ld8(const unsigned short* p) {
  short4 a = *(const short4*)p;
  short4 b = *(const short4*)(p + 4);
  bf16x8_t v = {a.x, a.y, a.z, a.w, b.x, b.y, b.z, b.w};
  return v;
}

// ---------------------------------------------------------------------------
__global__ void detect_kernel(const void* x, int* flag) {
  __shared__ int cnt;
  if (threadIdx.x == 0) cnt = 0;
  __syncthreads();
  const unsigned short* u = (const unsigned short*)x;
  int wild = 0;
  for (int i = threadIdx.x; i < 4096; i += 256) {
    int e = (u[i] >> 7) & 0xFF;
    wild += (e >= 140);
  }
  atomicAdd(&cnt, wild);
  __syncthreads();
  if (threadIdx.x == 0) *flag = (cnt > 100) ? 1 : 0;
}

__global__ void cvt_all(const void* qkv_w, const void* proj_w, const void* proj_b,
                        unsigned short* wb, unsigned short* pw, float* pbf,
                        const int* flag) {
  const int W3 = 3 * CC * CC, W1 = CC * CC;
  int i = blockIdx.x * 256 + threadIdx.x;
  const int f32 = *flag;
  if (i < W3) {
    wb[i] = f32 ? f2b(((const float*)qkv_w)[i]) : ((const unsigned short*)qkv_w)[i];
  } else if (i < W3 + W1) {
    int j = i - W3;
    pw[j] = f32 ? f2b(((const float*)proj_w)[j]) : ((const unsigned short*)proj_w)[j];
  } else if (i < W3 + W1 + CC) {
    int j = i - W3 - W1;
    pbf[j] = ldmix(proj_b, j, f32);
  }
}

// convert a chunk of x (rows [row_off, row_off+rows)) to bf16, 8 elems/thread
__global__ void cvt_x(const void* __restrict__ x, size_t elem_off,
                      unsigned short* __restrict__ xb, int n8,
                      const int* __restrict__ flag) {
  const int i = blockIdx.x * 256 + threadIdx.x;
  if (i >= n8) return;
  const size_t src = elem_off + (size_t)i * 8;
  bf16x8_t v;
  if (*flag) {
    const float* xp = (const float*)x + src;
    float4 u0 = *(const float4*)xp;
    float4 u1 = *(const float4*)(xp + 4);
    v = bf16x8_t{(short)f2b(u0.x), (short)f2b(u0.y), (short)f2b(u0.z),
                 (short)f2b(u0.w), (short)f2b(u1.x), (short)f2b(u1.y),
                 (short)f2b(u1.z), (short)f2b(u1.w)};
  } else {
    v = *(const bf16x8_t*)((const unsigned short*)x + src);
  }
  *(bf16x8_t*)(xb + (size_t)i * 8) = v;
}

// ---------------------------------------------------------------------------
// qkv_gemm: 128x128 LDS-staged MFMA GEMM on bf16 xb (chunk-local) @ wb^T.
// 1-D grid, XCD-swizzled: all 18 col-tiles of a row-tile on one XCD.
// ---------------------------------------------------------------------------
__global__ __launch_bounds__(256, 4) void qkv_gemm(
    const unsigned short* __restrict__ xb,
    const unsigned short* __restrict__ wb,
    unsigned short* __restrict__ qkvc, int Mc, int bc, int nRow) {
  const int xcd = blockIdx.x & 7;
  const int seq = blockIdx.x >> 3;
  const int colt = seq % 18;
  const int rowt = (seq / 18) * 8 + xcd;
  if (rowt >= nRow) return;
  const int m0 = rowt * 128;
  const int n0 = colt * 128;

  __shared__ unsigned short As[4096];
  __shared__ unsigned short Bs[4096];
  const int lane = threadIdx.x & 63;
  const int wave = threadIdx.x >> 6;
  const int l16  = lane & 15;
  const int quad = lane >> 4;
  const int wm = wave >> 1, wn = wave & 1;
  f32x4_t acc[4][4] = {};
  for (int kt = 0; kt < 24; kt++) {
    const int k0 = kt * 32;
    __syncthreads();
    #pragma unroll
    for (int ch = threadIdx.x; ch < 512; ch += 256) {
      int row = ch >> 2, kg = ch & 3;
      int gr = m0 + row; if (gr >= Mc) gr = Mc - 1;
      *(bf16x8_t*)&As[(row >> 4) * 512 + (row & 15) * 32 + kg * 8] =
          *(const bf16x8_t*)(xb + (size_t)gr * CC + k0 + kg * 8);
    }
    #pragma unroll
    for (int ch = threadIdx.x; ch < 512; ch += 256) {
      int row = ch >> 2, kg = ch & 3;
      *(bf16x8_t*)&Bs[(row >> 4) * 512 + (row & 15) * 32 + kg * 8] =
          *(const bf16x8_t*)(wb + (size_t)(n0 + row) * CC + k0 + kg * 8);
    }
    __syncthreads();
    bf16x8_t afr[4], bfr[4];
    #pragma unroll
    for (int r = 0; r < 4; r++)
      afr[r] = *(const bf16x8_t*)&As[(wm * 4 + r) * 512 + l16 * 32 + quad * 8];
    #pragma unroll
    for (int c = 0; c < 4; c++)
      bfr[c] = *(const bf16x8_t*)&Bs[(wn * 4 + c) * 512 + l16 * 32 + quad * 8];
    #pragma unroll
    for (int r = 0; r < 4; r++)
      #pragma unroll
      for (int c = 0; c < 4; c++)
        acc[r][c] = __builtin_amdgcn_mfma_f32_16x16x32_bf16(afr[r], bfr[c],
                                                            acc[r][c], 0, 0, 0);
  }
  #pragma unroll
  for (int c = 0; c < 4; c++) {
    const int col = n0 + wn * 64 + c * 16 + l16;
    const int s = col / CC;
    const int rem = col - s * CC;
    const int hc = rem >> 6, d = rem & 63;
    #pragma unroll
    for (int r = 0; r < 4; r++) {
      #pragma unroll
      for (int i = 0; i < 4; i++) {
        const int m = m0 + wm * 64 + r * 16 + quad * 4 + i;
        if (m < Mc) {
          const int bb = m / NN, n = m - bb * NN;
          qkvc[((((size_t)s * bc + bb) * HH + hc) * NN + n) * DD + d] =
              f2b(acc[r][c][i]);
        }
      }
    }
  }
}

// ---------------------------------------------------------------------------
// proj_gemm: 128x128 LDS-staged MFMA GEMM from bf16 ws, dual-dtype store.
// XCD-swizzled like qkv_gemm (6 col-tiles).
// ---------------------------------------------------------------------------
__global__ __launch_bounds__(256, 4) void proj_gemm(
    const unsigned short* __restrict__ Yc,
    const unsigned short* __restrict__ pw,
    const float* __restrict__ pbf,
    void* __restrict__ out, size_t out_off, int Mc, int nRow,
    const int* __restrict__ flag) {
  const int xcd = blockIdx.x & 7;
  const int seq = blockIdx.x >> 3;
  const int colt = seq % 6;
  const int rowt = (seq / 6) * 8 + xcd;
  if (rowt >= nRow) return;
  const int m0 = rowt * 128;
  const int n0 = colt * 128;

  __shared__ unsigned short As[4096];
  __shared__ unsigned short Bs[4096];
  const int lane = threadIdx.x & 63;
  const int wave = threadIdx.x >> 6;
  const int l16  = lane & 15;
  const int quad = lane >> 4;
  const int wm = wave >> 1, wn = wave & 1;
  f32x4_t acc[4][4] = {};
  for (int kt = 0; kt < 24; kt++) {
    const int k0 = kt * 32;
    __syncthreads();
    #pragma unroll
    for (int ch = threadIdx.x; ch < 512; ch += 256) {
      int row = ch >> 2, kg = ch & 3;
      int gr = m0 + row; if (gr >= Mc) gr = Mc - 1;
      *(bf16x8_t*)&As[(row >> 4) * 512 + (row & 15) * 32 + kg * 8] =
          *(const bf16x8_t*)(Yc + (size_t)gr * CC + k0 + kg * 8);
    }
    #pragma unroll
    for (int ch = threadIdx.x; ch < 512; ch += 256) {
      int row = ch >> 2, kg = ch & 3;
      *(bf16x8_t*)&Bs[(row >> 4) * 512 + (row & 15) * 32 + kg * 8] =
          *(const bf16x8_t*)(pw + (size_t)(n0 + row) * CC + k0 + kg * 8);
    }
    __syncthreads();
    bf16x8_t afr[4], bfr[4];
    #pragma unroll
    for (int r = 0; r < 4; r++)
      afr[r] = *(const bf16x8_t*)&As[(wm * 4 + r) * 512 + l16 * 32 + quad * 8];
    #pragma unroll
    for (int c = 0; c < 4; c++)
      bfr[c] = *(const bf16x8_t*)&Bs[(wn * 4 + c) * 512 + l16 * 32 + quad * 8];
    #pragma unroll
    for (int r = 0; r < 4; r++)
      #pragma unroll
      for (int c = 0; c < 4; c++)
        acc[r][c] = __builtin_amdgcn_mfma_f32_16x16x32_bf16(afr[r], bfr[c],
                                                            acc[r][c], 0, 0, 0);
  }
  const int f32 = *flag;
  #pragma unroll
  for (int c = 0; c < 4; c++) {
    const int col = n0 + wn * 64 + c * 16 + l16;
    const float bv = pbf[col];
    #pragma unroll
    for (int r = 0; r < 4; r++) {
      #pragma unroll
      for (int i = 0; i < 4; i++) {
        const int m = m0 + wm * 64 + r * 16 + quad * 4 + i;
        if (m < Mc) {
          const float val = acc[r][c][i] + bv;
          const size_t oi = out_off + (size_t)m * CC + col;
          if (f32) ((float*)out)[oi] = val;
          else ((unsigned short*)out)[oi] = f2b(val);
        }
      }
    }
  }
}

// ---------------------------------------------------------------------------
// MFMA attention (R7/R8 structure). Grid (bc*HH); 4 waves/block; each wave
// loops q-strips si = it*4+wave (13 strips of 16 rows). LDS 54,272 B.
// ---------------------------------------------------------------------------
__global__ __launch_bounds__(256, 3) void attn_kernel(
    const unsigned short* __restrict__ qkvc, int bc,
    unsigned short* __restrict__ Yc) {
  const int bh = blockIdx.x;
  const int bb = bh / HH;
  const int h  = bh % HH;
  const size_t mat = (size_t)bc * HH * NN * DD;
  const unsigned short* q = qkvc + ((size_t)bb * HH + h) * NN * DD;
  const unsigned short* k = q + mat;
  const unsigned short* v = q + 2 * mat;

  __shared__ unsigned short Vt[DD * VST];     // 27,136 B (V^T, zero-padded)
  __shared__ unsigned short Pl[4][16 * VST];  // 27,136 B (per-wave P strip)

  const int lane = threadIdx.x & 63;
  const int wave = threadIdx.x >> 6;
  const int l16  = lane & 15;
  const int quad = lane >> 4;

  // stage V^T once: Vt[d=lane][key], keys 197..211 zeroed
  #pragma unroll
  for (int it = 0; it < 53; it++) {
    const int key = it * 4 + wave;
    unsigned short val = (key < NN) ? v[(size_t)key * DD + lane]
                                    : (unsigned short)0;
    Vt[lane * VST + key] = val;
  }
  __syncthreads();

  unsigned short* Pw = &Pl[wave][0];

  for (int it = 0; it < 4; it++) {
    const int si = it * 4 + wave;
    if (si >= 13) break;          // no barriers inside the loop: safe
    const int q0 = si * 16;

    int qrow = q0 + l16; if (qrow >= NN) qrow = NN - 1;
    const unsigned short* qp = q + (size_t)qrow * DD + quad * 8;
    const bf16x8_t aq0 = *(const bf16x8_t*)qp;
    const bf16x8_t aq1 = *(const bf16x8_t*)(qp + 32);

    // S strip: 16 q-rows x 208 keys, 26 MFMAs, K frags from global (L1/L2)
    f32x4_t sc[13];
    #pragma unroll
    for (int ct = 0; ct < 13; ct++) {
      int key = ct * 16 + l16; if (key >= NN) key = NN - 1;
      const unsigned short* kp = k + (size_t)key * DD + quad * 8;
      const bf16x8_t b0 = *(const bf16x8_t*)kp;
      const bf16x8_t b1 = *(const bf16x8_t*)(kp + 32);
      f32x4_t t = {0.f, 0.f, 0.f, 0.f};
      t = __builtin_amdgcn_mfma_f32_16x16x32_bf16(aq0, b0, t, 0, 0, 0);
      t = __builtin_amdgcn_mfma_f32_16x16x32_bf16(aq1, b1, t, 0, 0, 0);
      sc[ct] = t;
    }

    // softmax per row (row = quad*4+i), reduce across l16 via shfl
    float inv_l[4];
    #pragma unroll
    for (int i = 0; i < 4; i++) {
      float m = -1e30f;
      #pragma unroll
      for (int ct = 0; ct < 13; ct++)
        if (ct < 12 || l16 < 5) m = fmaxf(m, sc[ct][i] * SCALE_F);
      #pragma unroll
      for (int d = 1; d < 16; d <<= 1) m = fmaxf(m, __shfl_xor(m, d, 64));
      float s = 0.f;
      #pragma unroll
      for (int ct = 0; ct < 13; ct++) {
        const float p = (ct < 12 || l16 < 5) ? __expf(sc[ct][i] * SCALE_F - m)
                                             : 0.f;
        sc[ct][i] = p;
        s += p;
      }
      #pragma unroll
      for (int d = 1; d < 16; d <<= 1) s += __shfl_xor(s, d, 64);
      inv_l[i] = 1.0f / s;
    }

    // P -> per-wave LDS (A-layout, cols 0..207); same-wave ordering only
    #pragma unroll
    for (int i = 0; i < 4; i++) {
      const int ro = (quad * 4 + i) * VST;
      #pragma unroll
      for (int ct = 0; ct < 13; ct++)
        Pw[ro + ct * 16 + l16] = f2b(sc[ct][i]);
    }

    // O strip = P(16x208) @ V(208x64): 6 full 32-key chunks + 16-key tail
    f32x4_t oc[4] = {};
    #pragma unroll
    for (int ks = 0; ks < 6; ks++) {
      const bf16x8_t ap = ld8(&Pw[l16 * VST + ks * 32 + quad * 8]);
      #pragma unroll
      for (int dt = 0; dt < 4; dt++) {
        const bf16x8_t bv = ld8(&Vt[(dt * 16 + l16) * VST + ks * 32 + quad * 8]);
        oc[dt] = __builtin_amdgcn_mfma_f32_16x16x32_bf16(ap, bv, oc[dt], 0, 0, 0);
      }
    }
    {  // tail keys 192..207: quads 0,1 carry data, quads 2,3 zero frags
      const bf16x8_t zz = {};
      bf16x8_t ap = zz;
      if (quad < 2) ap = ld8(&Pw[l16 * VST + 192 + quad * 8]);
      #pragma unroll
      for (int dt = 0; dt < 4; dt++) {
        bf16x8_t bv = zz;
        if (quad < 2) bv = ld8(&Vt[(dt * 16 + l16) * VST + 192 + quad * 8]);
        oc[dt] = __builtin_amdgcn_mfma_f32_16x16x32_bf16(ap, bv, oc[dt], 0, 0, 0);
      }
    }

    #pragma unroll
    for (int i = 0; i < 4; i++) {
      const int n = q0 + quad * 4 + i;
      if (n < NN) {
        unsigned short* yp = Yc + ((size_t)bb * NN + n) * CC + h * DD;
        #pragma unroll
        for (int dt = 0; dt < 4; dt++)
          yp[dt * 16 + l16] = f2b(oc[dt][i] * inv_l[i]);
      }
    }
  }
}

// ---------------------------------------------------------------------------
// Top-k path, fp32-exact (matches np reference ranking).
// qcls: one wave per output qc[b][i], lanes along K (coalesced).
// ---------------------------------------------------------------------------
__global__ __launch_bounds__(256, 4) void qcls_kernel(
    const void* __restrict__ x, const void* __restrict__ qkv_w,
    float* __restrict__ qc, const int* __restrict__ flag) {
  const int idx = blockIdx.x * 4 + (threadIdx.x >> 6);
  if (idx >= BB * CC) return;
  const int b = idx / CC, i = idx - b * CC;
  const int lane = threadIdx.x & 63;
  const int f32 = *flag;
  const size_t xr = (size_t)b * NN * CC;
  const size_t wr = (size_t)i * CC;
  float p = 0.f;
  #pragma unroll
  for (int j = 0; j < 12; j++)
    p += ldmix(x, xr + j * 64 + lane, f32) * ldmix(qkv_w, wr + j * 64 + lane, f32);
  #pragma unroll
  for (int m = 32; m; m >>= 1) p += __shfl_xor(p, m, 64);
  if (lane == 0) qc[(size_t)b * CC + i] = p;
}

__global__ __launch_bounds__(256, 4) void gmat_kernel(
    const void* __restrict__ qkv_w, const float* __restrict__ qc,
    float* __restrict__ g, const int* __restrict__ flag) {
  const int b = blockIdx.x, h = blockIdx.y;
  const int f32 = *flag;
  __shared__ float qh[DD];
  if (threadIdx.x < DD) qh[threadIdx.x] = qc[(size_t)b * CC + h * DD + threadIdx.x];
  __syncthreads();
  const int c0 = threadIdx.x, c1 = c0 + 256, c2 = c1 + 256;
  float a0 = 0.f, a1 = 0.f, a2 = 0.f;
  for (int d = 0; d < DD; d++) {
    const size_t ro = (size_t)(CC + h * DD + d) * CC;
    const float qv = qh[d];
    a0 += ldmix(qkv_w, ro + c0, f32) * qv;
    a1 += ldmix(qkv_w, ro + c1, f32) * qv;
    a2 += ldmix(qkv_w, ro + c2, f32) * qv;
  }
  float* gb = g + ((size_t)b * HH + h) * CC;
  gb[c0] = a0; gb[c1] = a1; gb[c2] = a2;
}

__global__ __launch_bounds__(256, 4) void score_kernel(
    const void* __restrict__ x, const float* __restrict__ g,
    float* __restrict__ wscore, const int* __restrict__ flag) {
  const int idx = blockIdx.x * 4 + (threadIdx.x >> 6);
  if (idx >= BB * NN) return;
  const int b = idx / NN, n = idx - b * NN;
  const int lane = threadIdx.x & 63;
  const int f32 = *flag;
  const size_t xr = ((size_t)b * NN + n) * CC;
  float xv[12];
  #pragma unroll
  for (int j = 0; j < 12; j++) xv[j] = ldmix(x, xr + j * 64 + lane, f32);
  const float* gb = g + (size_t)b * HH * CC;
  float acc = 0.f;
  #pragma unroll
  for (int h = 0; h < HH; h++) {
    const float* gh = gb + (size_t)h * CC;
    float p = 0.f;
    #pragma unroll
    for (int j = 0; j < 12; j++) p += xv[j] * gh[j * 64 + lane];
    #pragma unroll
    for (int m = 32; m; m >>= 1) p += __shfl_xor(p, m, 64);
    acc += fabsf(p);
  }
  if (lane == 0) wscore[(size_t)b * NN + n] = acc;
}

__global__ __launch_bounds__(256, 4) void rank_kernel(
    const float* __restrict__ wscore, void* __restrict__ out,
    const int* __restrict__ flag) {
  const int b = blockIdx.x;
  const int f32 = *flag;
  __shared__ float wgt[NN];
  __shared__ int   rank[NN];
  if (threadIdx.x < NN) wgt[threadIdx.x] = wscore[(size_t)b * NN + threadIdx.x];
  __syncthreads();
  const int n = threadIdx.x;
  if (n < NN) {
    float wi = wgt[n];
    int rk = 0;
    for (int j = 0; j < NN; j++) {
      float wj = wgt[j];
      rk += (wj > wi) || (wj == wi && j < n);   // stable top_k tie-break
    }
    rank[n] = rk;
  }
  __syncthreads();
  if (n < NN && rank[n] < KEEP) {
    int pos = 0;
    for (int j = 0; j < n; j++) pos += (rank[j] < KEEP);
    const size_t oi = OUT0_ELEMS + (size_t)b * KEEP + pos;
    if (f32) ((float*)out)[oi] = (float)n;
    else ((unsigned short*)out)[oi] = f2b((float)n);
  }
}

// ---------------------------------------------------------------------------
extern "C" void kernel_launch(void* const* d_in, const int* in_sizes, int n_in,
                              void* d_out, int out_size, void* d_ws, size_t ws_size,
                              hipStream_t stream) {
  const void* x      = d_in[0];
  const void* qkv_w  = d_in[1];
  const void* proj_w = d_in[2];
  const void* proj_b = d_in[3];

  char* wsb = (char*)d_ws;
  int* flag = (int*)wsb;
  unsigned short* wb  = (unsigned short*)(wsb + 256);
  unsigned short* pw  = (unsigned short*)(wsb + 256 + 3538944);
  float* pbf    = (float*)(wsb + 256 + 3538944 + 1179648);
  float* qc     = (float*)(wsb + 256 + 3538944 + 1179648 + 4096);
  float* g      = qc + (size_t)BB * CC;
  float* wscore = g + (size_t)BB * HH * CC;
  const size_t fixed = 256 + 3538944 + 1179648 + 4096 + 196608 + 2359296 + 51200;
  char* chunk = wsb + fixed;

  const size_t per_batch = (size_t)NN * CC * 2       // xb_c
                         + 3ull * HH * NN * DD * 2   // qkvc
                         + (size_t)NN * CC * 2;      // Yc  = 1,512,960
  int Bc = BB;
  while (Bc > 1 && fixed + (size_t)Bc * per_batch > ws_size) Bc >>= 1;

  unsigned short* xb   = (unsigned short*)chunk;
  unsigned short* qkvc = xb + (size_t)Bc * NN * CC;
  unsigned short* Yc   = qkvc + 3ull * Bc * HH * NN * DD;

  detect_kernel<<<1, 256, 0, stream>>>(x, flag);
  const int cvt_n = 3 * CC * CC + CC * CC + CC;
  cvt_all<<<(cvt_n + 255) / 256, 256, 0, stream>>>(qkv_w, proj_w, proj_b,
                                                   wb, pw, pbf, flag);

  // top-k path (fp32-exact, independent of the bf16 pipeline)
  qcls_kernel<<<(BB * CC + 3) / 4, 256, 0, stream>>>(x, qkv_w, qc, flag);
  gmat_kernel<<<dim3(BB, HH), 256, 0, stream>>>(qkv_w, qc, g, flag);
  score_kernel<<<(BB * NN + 3) / 4, 256, 0, stream>>>(x, g, wscore, flag);
  rank_kernel<<<BB, 256, 0, stream>>>(wscore, d_out, flag);

  const int nChunks = (BB + Bc - 1) / Bc;
  for (int cb = 0; cb < nChunks; cb++) {
    const int b0 = cb * Bc;
    const int bc = (BB - b0 < Bc) ? (BB - b0) : Bc;
    const int Mc = bc * NN;
    const int n8 = Mc * CC / 8;   // Mc*CC is a multiple of 8 (CC=768)
    cvt_x<<<(n8 + 255) / 256, 256, 0, stream>>>(
        x, (size_t)b0 * NN * CC, xb, n8, flag);
    const int nRowQ = (Mc + 127) / 128;
    const int gridQ = 8 * 18 * ((nRowQ + 7) / 8);
    qkv_gemm<<<gridQ, 256, 0, stream>>>(xb, wb, qkvc, Mc, bc, nRowQ);
    attn_kernel<<<dim3(bc * HH), 256, 0, stream>>>(qkvc, bc, Yc);
    const int gridP = 8 * 6 * ((nRowQ + 7) / 8);
    proj_gemm<<<gridP, 256, 0, stream>>>(
        Yc, pw, pbf, d_out, (size_t)b0 * NN * CC, Mc, nRowQ, flag);
  }
}